// Round 1
// baseline (2117.182 us; speedup 1.0000x reference)
//
#include <hip/hip_runtime.h>
#include <hip/hip_bf16.h>
#include <math.h>

#define NN 16
#define PP 128
#define CIN 64
#define CC 128
#define HID 32
#define NEGV (-10000.0f)
#define EPS 1e-5f

__device__ __forceinline__ float dot4(float4 a, float4 b) {
  return a.x*b.x + a.y*b.y + a.z*b.z + a.w*b.w;
}

// 2-value butterfly reduce across NWAVES*64 threads (values may be duplicated
// across groups; caller divides by thread count).
template<int NWAVES>
__device__ __forceinline__ void bred2(float& a, float& b, float* red, int t) {
  #pragma unroll
  for (int m = 32; m; m >>= 1) { a += __shfl_xor(a, m); b += __shfl_xor(b, m); }
  __syncthreads();
  if ((t & 63) == 0) { red[2*(t>>6)] = a; red[2*(t>>6)+1] = b; }
  __syncthreads();
  float ra = 0.f, rb = 0.f;
  #pragma unroll
  for (int w = 0; w < NWAVES; ++w) { ra += red[2*w]; rb += red[2*w+1]; }
  a = ra; b = rb;
}

// ---------------- K1: q,k,v projections ----------------
extern "C" __global__ void __launch_bounds__(128)
k_qkv(const float* __restrict__ x,
      const float* __restrict__ wq, const float* __restrict__ bq,
      const float* __restrict__ wk, const float* __restrict__ bk,
      const float* __restrict__ wv, const float* __restrict__ bv,
      float* __restrict__ q, float* __restrict__ k, float* __restrict__ v) {
  const int row = blockIdx.x;          // n*P + idx
  const int c = threadIdx.x;           // 0..127
  __shared__ __align__(16) float xs[CIN];
  if (c < CIN) xs[c] = x[row*CIN + c];
  __syncthreads();
  const float4* wq4 = (const float4*)(wq + c*CIN);
  const float4* wk4 = (const float4*)(wk + c*CIN);
  const float4* wv4 = (const float4*)(wv + c*CIN);
  const float4* xs4 = (const float4*)xs;
  float sq = 0.f, sk = 0.f, sv = 0.f;
  #pragma unroll
  for (int d = 0; d < CIN/4; ++d) {
    float4 xv = xs4[d];
    sq += dot4(wq4[d], xv);
    sk += dot4(wk4[d], xv);
    sv += dot4(wv4[d], xv);
  }
  q[row*CC + c] = sq + bq[c];
  k[row*CC + c] = sk + bk[c];
  v[row*CC + c] = sv + bv[c];
}

// ---------------- K2: fused pe-MLP + r_qk MLP + online softmax -> x_out ----
// block = 256 threads: c = t&127, g = t>>7 (each group dots 64 of 128).
// w1/w2 rows + pe2 row held in registers; online softmax per (c) over j.
extern "C" __global__ void __launch_bounds__(256, 2)
k_attn(const float* __restrict__ q, const float* __restrict__ k,
       const float* __restrict__ v, const float* __restrict__ p,
       const float* __restrict__ U,
       const float* __restrict__ pe1, const float* __restrict__ pe2,
       const float* __restrict__ ln1g, const float* __restrict__ ln1b,
       const float* __restrict__ w1, const float* __restrict__ b1,
       const float* __restrict__ ln2g, const float* __restrict__ ln2b,
       const float* __restrict__ w2, const float* __restrict__ b2,
       float* __restrict__ xout) {
  const int nb = blockIdx.x;
  const int n = nb >> 7, i = nb & 127;
  const int t = threadIdx.x;
  const int c = t & 127;
  const int g = t >> 7;

  __shared__ __align__(16) float p_sh[PP*4];
  __shared__ __align__(16) float h0_sh[HID];
  __shared__ __align__(16) float a_sh[CC];
  __shared__ __align__(16) float a2_sh[CC];
  __shared__ __align__(16) float scr[2][CC];
  __shared__ __align__(16) float red[8];

  for (int idx = t; idx < PP*4; idx += 256) p_sh[idx] = p[n*PP*4 + idx];

  // weights in registers: 16+16+8 float4 = 160 VGPRs
  float4 w1r[16], w2r[16], pe2r[8];
  {
    const float4* w1p = (const float4*)(w1 + c*CC + 64*g);
    const float4* w2p = (const float4*)(w2 + c*CC + 64*g);
    #pragma unroll
    for (int m = 0; m < 16; ++m) { w1r[m] = w1p[m]; w2r[m] = w2p[m]; }
    const float4* pep = (const float4*)(pe2 + c*HID);
    #pragma unroll
    for (int m = 0; m < 8; ++m) pe2r[m] = pep[m];
  }
  float pe1r0=0.f, pe1r1=0.f, pe1r2=0.f, pe1r3=0.f;
  if (t < HID) {
    pe1r0 = pe1[t*4]; pe1r1 = pe1[t*4+1]; pe1r2 = pe1[t*4+2]; pe1r3 = pe1[t*4+3];
  }

  const float ki    = k[(n*PP + i)*CC + c];
  const float g1c   = ln1g[c], b1c = ln1b[c];
  const float g2c   = ln2g[c], b2c = ln2b[c];
  const float bias1 = b1[c],  bias2 = b2[c];

  __syncthreads();
  const float pi0 = p_sh[i*4+0], pi1 = p_sh[i*4+1];
  const float pi2 = p_sh[i*4+2], pi3 = p_sh[i*4+3];
  const bool  mask_i = (pi0 == 0.0f);

  float m_run = -INFINITY, s_run = 0.f, acc = 0.f;

  const float* qn = q + n*PP*CC;
  const float* vn = v + n*PP*CC;
  const float* Un = U + ((size_t)(n*PP + i))*PP*CC;

  for (int j = 0; j < PP; ++j) {
    // --- pe MLP stage 1: h0 = relu(ln(pij @ pe1.T)) on threads 0..31 ---
    if (t < HID) {
      float pj0 = pi0 - p_sh[j*4+0], pj1 = pi1 - p_sh[j*4+1];
      float pj2 = pi2 - p_sh[j*4+2], pj3 = pi3 - p_sh[j*4+3];
      float hu = pe1r0*pj0 + pe1r1*pj1 + pe1r2*pj2 + pe1r3*pj3;
      float s1 = hu, s2 = hu*hu;
      #pragma unroll
      for (int m = 16; m; m >>= 1) { s1 += __shfl_xor(s1, m, 32); s2 += __shfl_xor(s2, m, 32); }
      float mu = s1 * (1.0f/HID);
      float rs = rsqrtf(s2*(1.0f/HID) - mu*mu + EPS);
      h0_sh[t] = fmaxf((hu - mu)*rs, 0.f);
    }
    __syncthreads();

    // --- eqpe = relu(ln(h0 @ pe2.T)) ---
    float e_c = 0.f;
    {
      const float4* h4 = (const float4*)h0_sh;
      #pragma unroll
      for (int m = 0; m < 8; ++m) e_c += dot4(pe2r[m], h4[m]);
    }
    float sa = e_c, sb = e_c*e_c;
    bred2<4>(sa, sb, red, t);                    // duplicated x2: /256 == /128
    float mu = sa*(1.0f/256.f);
    float rs = rsqrtf(sb*(1.0f/256.f) - mu*mu + EPS);
    const float eq = fmaxf((e_c - mu)*rs, 0.f);

    // --- r_qk and xv ---
    const float Uv = Un[j*CC + c];
    const float r_ = ki - qn[j*CC + c] + Uv + eq;
    const float xv = vn[j*CC + c] + Uv + eq;

    // --- LN1 + relu ---
    sa = r_; sb = r_*r_;
    bred2<4>(sa, sb, red, t);
    mu = sa*(1.0f/256.f);
    rs = rsqrtf(sb*(1.0f/256.f) - mu*mu + EPS);
    const float a_ = fmaxf((r_ - mu)*rs*g1c + b1c, 0.f);
    if (g == 0) a_sh[c] = a_;
    __syncthreads();

    // --- GEMV1: h = a @ w1.T (split dot across 2 groups) ---
    float pt = 0.f;
    {
      const float4* a4 = (const float4*)(a_sh + 64*g);
      #pragma unroll
      for (int m = 0; m < 16; ++m) pt += dot4(w1r[m], a4[m]);
    }
    scr[g][c] = pt;
    __syncthreads();
    const float bv = scr[0][c] + scr[1][c] + bias1;

    // --- LN2 + relu ---
    sa = bv; sb = bv*bv;
    bred2<4>(sa, sb, red, t);
    mu = sa*(1.0f/256.f);
    rs = rsqrtf(sb*(1.0f/256.f) - mu*mu + EPS);
    const float a2 = fmaxf((bv - mu)*rs*g2c + b2c, 0.f);
    if (g == 0) a2_sh[c] = a2;
    __syncthreads();

    // --- GEMV2: logits = a2 @ w2.T ---
    float pt2 = 0.f;
    {
      const float4* a4 = (const float4*)(a2_sh + 64*g);
      #pragma unroll
      for (int m = 0; m < 16; ++m) pt2 += dot4(w2r[m], a4[m]);
    }
    scr[g][c] = pt2;
    __syncthreads();
    float l = scr[0][c] + scr[1][c] + bias2;
    if (mask_i) l = NEGV;

    // --- online softmax over j (per channel c) ---
    const float mn = fmaxf(m_run, l);
    const float eo = __expf(m_run - mn);
    const float f  = __expf(l - mn);
    s_run = s_run*eo + f;
    acc   = acc*eo + f*xv;
    m_run = mn;
  }

  if (g == 0) xout[(n*PP + i)*CC + c] = acc / s_run;
}

// ---------------- K3: A[r,u] = e1[u,0:128] . xout[r]; B[r,u] = e1[u,128:256] . xout[r]
extern "C" __global__ void __launch_bounds__(64)
k_e1(const float* __restrict__ xout, const float* __restrict__ e1,
     float* __restrict__ A, float* __restrict__ B) {
  const int row = blockIdx.x;
  const int t = threadIdx.x;
  __shared__ __align__(16) float xs[CC];
  xs[t]      = xout[row*CC + t];
  xs[t + 64] = xout[row*CC + t + 64];
  __syncthreads();
  const int u = t & 31;
  const int half = t >> 5;
  const float* er = e1 + u*257 + half*128;   // stride 257 -> rows unaligned; scalar loop
  float s = 0.f;
  for (int cc2 = 0; cc2 < CC; ++cc2) s += xs[cc2]*er[cc2];
  (half ? B : A)[row*HID + u] = s;
}

// ---------------- K4: edge-MLP + LN + scalar softmax over j -> new_p -------
// block = 128 threads, thread j owns row j; two-pass LN with mij recompute.
extern "C" __global__ void __launch_bounds__(128)
k_newp(const float* __restrict__ p, const float* __restrict__ A,
       const float* __restrict__ Bm, const float* __restrict__ e1,
       const float* __restrict__ e2, const float* __restrict__ x1,
       const float* __restrict__ x1b, const float* __restrict__ x2,
       const float* __restrict__ x2b, float* __restrict__ outp) {
  const int nb = blockIdx.x;
  const int n = nb >> 7, i = nb & 127;
  const int j = threadIdx.x;

  __shared__ __align__(16) float p_sh[PP*4];
  __shared__ __align__(16) float e2_sh[CC*HID];    // e2[c][u], row-contig
  __shared__ __align__(16) float x1T_sh[CC*HID];   // x1T[c][u]
  __shared__ __align__(16) float Ai[HID];
  __shared__ __align__(16) float e1l[HID];
  __shared__ __align__(16) float x1bs[HID];
  __shared__ __align__(16) float x2s[HID];
  __shared__ __align__(16) float red[16];

  ((float4*)p_sh)[j] = ((const float4*)(p + n*PP*4))[j];
  for (int idx = j; idx < CC*HID; idx += PP) e2_sh[idx] = e2[idx];
  for (int idx = j; idx < CC*HID; idx += PP) {
    int u = idx >> 7, cc2 = idx & 127;
    x1T_sh[cc2*HID + u] = x1[idx];
  }
  if (j < HID) {
    Ai[j]   = A[(n*PP + i)*HID + j];
    e1l[j]  = e1[j*257 + 256];
    x1bs[j] = x1b[j];
    x2s[j]  = x2[j];
  }
  __syncthreads();

  const float pi0 = p_sh[i*4+0], pi1 = p_sh[i*4+1];
  const float pi2 = p_sh[i*4+2], pi3 = p_sh[i*4+3];
  const bool  mask_i = (pi0 == 0.0f);
  const float pij0 = pi0 - p_sh[j*4+0], pij1 = pi1 - p_sh[j*4+1];
  const float pij2 = pi2 - p_sh[j*4+2], pij3 = pi3 - p_sh[j*4+3];
  float nv = pij3*pij3 - (pij0*pij0 + pij1*pij1 + pij2*pij2);
  if (mask_i) nv = 0.f;

  float h1[HID];
  {
    const float4* B4 = (const float4*)(Bm + (n*PP + j)*HID);
    #pragma unroll
    for (int u4 = 0; u4 < 8; ++u4) {
      float4 b4 = B4[u4];
      h1[4*u4+0] = fmaxf(Ai[4*u4+0] + b4.x + e1l[4*u4+0]*nv, 0.f);
      h1[4*u4+1] = fmaxf(Ai[4*u4+1] + b4.y + e1l[4*u4+1]*nv, 0.f);
      h1[4*u4+2] = fmaxf(Ai[4*u4+2] + b4.z + e1l[4*u4+2]*nv, 0.f);
      h1[4*u4+3] = fmaxf(Ai[4*u4+3] + b4.w + e1l[4*u4+3]*nv, 0.f);
    }
  }

  // pass 1: LN stats of mij (masked)
  float sum = 0.f, ss = 0.f;
  for (int cc2 = 0; cc2 < CC; ++cc2) {
    const float4* e4 = (const float4*)(e2_sh + cc2*HID);
    float m_ = 0.f;
    #pragma unroll
    for (int u4 = 0; u4 < 8; ++u4) {
      float4 w4 = e4[u4];
      m_ += w4.x*h1[4*u4+0] + w4.y*h1[4*u4+1] + w4.z*h1[4*u4+2] + w4.w*h1[4*u4+3];
    }
    m_ = fmaxf(m_, 0.f);
    if (mask_i) m_ = NEGV;
    sum += m_; ss += m_*m_;
  }
  const float mu = sum*(1.0f/CC);
  const float rs = rsqrtf(ss*(1.0f/CC) - mu*mu + EPS);

  // pass 2: recompute mij, accumulate h2 = x1 @ ln(mij)
  float h2[HID];
  #pragma unroll
  for (int u = 0; u < HID; ++u) h2[u] = 0.f;
  for (int cc2 = 0; cc2 < CC; ++cc2) {
    const float4* e4 = (const float4*)(e2_sh + cc2*HID);
    float m_ = 0.f;
    #pragma unroll
    for (int u4 = 0; u4 < 8; ++u4) {
      float4 w4 = e4[u4];
      m_ += w4.x*h1[4*u4+0] + w4.y*h1[4*u4+1] + w4.z*h1[4*u4+2] + w4.w*h1[4*u4+3];
    }
    m_ = fmaxf(m_, 0.f);
    if (mask_i) m_ = NEGV;
    const float y = (m_ - mu)*rs;
    const float4* xr = (const float4*)(x1T_sh + cc2*HID);
    #pragma unroll
    for (int u4 = 0; u4 < 8; ++u4) {
      float4 w4 = xr[u4];
      h2[4*u4+0] += w4.x*y; h2[4*u4+1] += w4.y*y;
      h2[4*u4+2] += w4.z*y; h2[4*u4+3] += w4.w*y;
    }
  }
  float sj = x2b[0];
  #pragma unroll
  for (int u = 0; u < HID; ++u) sj += x2s[u]*fmaxf(h2[u] + x1bs[u], 0.f);
  sj = fmaxf(sj, 0.f);

  // softmax over j (block-wide) + weighted pij sums
  float mx = sj;
  #pragma unroll
  for (int m = 32; m; m >>= 1) mx = fmaxf(mx, __shfl_xor(mx, m));
  __syncthreads();
  if ((j & 63) == 0) red[j >> 6] = mx;
  __syncthreads();
  mx = fmaxf(red[0], red[1]);

  const float e = __expf(sj - mx);
  float v0 = e, v1 = e*pij0, v2 = e*pij1, v3 = e*pij2, v4 = e*pij3;
  #pragma unroll
  for (int m = 32; m; m >>= 1) {
    v0 += __shfl_xor(v0, m); v1 += __shfl_xor(v1, m); v2 += __shfl_xor(v2, m);
    v3 += __shfl_xor(v3, m); v4 += __shfl_xor(v4, m);
  }
  __syncthreads();
  if ((j & 63) == 0) {
    const int w = j >> 6;
    red[2 + w*5 + 0] = v0; red[2 + w*5 + 1] = v1; red[2 + w*5 + 2] = v2;
    red[2 + w*5 + 3] = v3; red[2 + w*5 + 4] = v4;
  }
  __syncthreads();
  v0 = red[2] + red[7];  v1 = red[3] + red[8];  v2 = red[4] + red[9];
  v3 = red[5] + red[10]; v4 = red[6] + red[11];

  float regc = 0.f;
  for (int jj = 0; jj < PP; ++jj) regc += (p_sh[jj*4] != 0.f) ? 1.f : 0.f;

  if (j < 4) {
    const float pid = p_sh[i*4 + j];
    const float num = (j == 0) ? v1 : (j == 1) ? v2 : (j == 2) ? v3 : v4;
    float val = pid + num/(v0*regc);
    if (pid == 0.f) val = 0.f;
    outp[(n*PP + i)*4 + j] = val;
  }
}

// ---------------- launcher ----------------
extern "C" void kernel_launch(void* const* d_in, const int* in_sizes, int n_in,
                              void* d_out, int out_size, void* d_ws, size_t ws_size,
                              hipStream_t stream) {
  const float* x    = (const float*)d_in[0];
  const float* p    = (const float*)d_in[1];
  const float* U    = (const float*)d_in[2];
  const float* wq   = (const float*)d_in[3];
  const float* bq   = (const float*)d_in[4];
  const float* wk   = (const float*)d_in[5];
  const float* bk   = (const float*)d_in[6];
  const float* wv   = (const float*)d_in[7];
  const float* bv   = (const float*)d_in[8];
  const float* ln1g = (const float*)d_in[9];
  const float* ln1b = (const float*)d_in[10];
  const float* w1   = (const float*)d_in[11];
  const float* b1   = (const float*)d_in[12];
  const float* ln2g = (const float*)d_in[13];
  const float* ln2b = (const float*)d_in[14];
  const float* w2   = (const float*)d_in[15];
  const float* b2   = (const float*)d_in[16];
  const float* pe1  = (const float*)d_in[17];
  const float* pe2  = (const float*)d_in[18];
  const float* e1   = (const float*)d_in[19];
  const float* e2   = (const float*)d_in[20];
  const float* x1   = (const float*)d_in[21];
  const float* x1b  = (const float*)d_in[22];
  const float* x2   = (const float*)d_in[23];
  const float* x2b  = (const float*)d_in[24];

  float* xout = (float*)d_out;           // N*P*C
  float* outp = xout + NN*PP*CC;         // N*P*4

  float* ws = (float*)d_ws;
  float* q  = ws;
  float* k  = q + NN*PP*CC;
  float* v  = k + NN*PP*CC;
  float* A  = v + NN*PP*CC;
  float* B  = A + NN*PP*HID;

  k_qkv <<<NN*PP, 128, 0, stream>>>(x, wq, bq, wk, bk, wv, bv, q, k, v);
  k_attn<<<NN*PP, 256, 0, stream>>>(q, k, v, p, U, pe1, pe2, ln1g, ln1b,
                                    w1, b1, ln2g, ln2b, w2, b2, xout);
  k_e1  <<<NN*PP, 64, 0, stream>>>(xout, e1, A, B);
  k_newp<<<NN*PP, 128, 0, stream>>>(p, A, B, e1, e2, x1, x1b, x2, x2b, outp);
}

// Round 2
// 1247.586 us; speedup vs baseline: 1.6970x; 1.6970x over previous
//
#include <hip/hip_runtime.h>
#include <hip/hip_bf16.h>
#include <math.h>

#define NN 16
#define PP 128
#define CIN 64
#define CC 128
#define HID 32
#define NEGV (-10000.0f)
#define EPS 1e-5f

__device__ __forceinline__ float dot4(float4 a, float4 b) {
  return a.x*b.x + a.y*b.y + a.z*b.z + a.w*b.w;
}

// ---------------- K1: q,k,v projections ----------------
extern "C" __global__ void __launch_bounds__(128)
k_qkv(const float* __restrict__ x,
      const float* __restrict__ wq, const float* __restrict__ bq,
      const float* __restrict__ wk, const float* __restrict__ bk,
      const float* __restrict__ wv, const float* __restrict__ bv,
      float* __restrict__ q, float* __restrict__ k, float* __restrict__ v) {
  const int row = blockIdx.x;
  const int c = threadIdx.x;
  __shared__ __align__(16) float xs[CIN];
  if (c < CIN) xs[c] = x[row*CIN + c];
  __syncthreads();
  const float4* wq4 = (const float4*)(wq + c*CIN);
  const float4* wk4 = (const float4*)(wk + c*CIN);
  const float4* wv4 = (const float4*)(wv + c*CIN);
  const float4* xs4 = (const float4*)xs;
  float sq = 0.f, sk = 0.f, sv = 0.f;
  #pragma unroll
  for (int d = 0; d < CIN/4; ++d) {
    float4 xv = xs4[d];
    sq += dot4(wq4[d], xv);
    sk += dot4(wk4[d], xv);
    sv += dot4(wv4[d], xv);
  }
  q[row*CC + c] = sq + bq[c];
  k[row*CC + c] = sk + bk[c];
  v[row*CC + c] = sv + bv[c];
}

// ===================== K2 (rewritten): j-parallel fused attention ==========
// Block: 512 threads = 8 waves. Lane map: wave=t>>6, jloc=(t&63)>>2, q=t&3.
// j = wave*16 + jloc (0..127). Each 4-lane group owns pair (i,j); lane q owns
// channels [32q, 32q+32). LayerNorms = 2x shfl_xor within the 4-lane group.
// Weights staged into 32KB LDS in halves (pe2, w1 lo/hi, w2 lo/hi); dots use
// register activations vs LDS-broadcast weight rows + 4-lane butterfly.

// One GEMV half-pass: W holds 64 rows (co_local = s*32+m, s in {0,1}); this
// thread contributes its 32-ci quarter; butterfly-sum across the 4-lane
// group; owner lane (q>>1 == pass, s == q&1) keeps co = 32*q + m.
__device__ __forceinline__ void gemv_half(const float* __restrict__ W,
                                          const float (&a)[32], float (&out)[32],
                                          int q, int pass) {
  const int cb = q*32;
  #pragma unroll
  for (int m = 0; m < 32; ++m) {
    float p0 = 0.f, p1 = 0.f;
    const float4* r0 = (const float4*)(W + m*CC + cb);
    const float4* r1 = (const float4*)(W + (32+m)*CC + cb);
    #pragma unroll
    for (int kk = 0; kk < 8; ++kk) {
      float4 w0 = r0[kk], w1v = r1[kk];
      p0 += w0.x*a[4*kk] + w0.y*a[4*kk+1] + w0.z*a[4*kk+2] + w0.w*a[4*kk+3];
      p1 += w1v.x*a[4*kk] + w1v.y*a[4*kk+1] + w1v.z*a[4*kk+2] + w1v.w*a[4*kk+3];
    }
    p0 += __shfl_xor(p0, 1); p1 += __shfl_xor(p1, 1);
    p0 += __shfl_xor(p0, 2); p1 += __shfl_xor(p1, 2);
    const float res = (q & 1) ? p1 : p0;
    if ((q >> 1) == pass) out[m] = res;
  }
}

// LN stats over 128 values spread as 32/lane across the 4-lane group.
__device__ __forceinline__ void ln_stats(const float (&v)[32], float& mu, float& rs) {
  float s1 = 0.f, s2 = 0.f;
  #pragma unroll
  for (int m = 0; m < 32; ++m) { s1 += v[m]; s2 += v[m]*v[m]; }
  s1 += __shfl_xor(s1, 1); s2 += __shfl_xor(s2, 1);
  s1 += __shfl_xor(s1, 2); s2 += __shfl_xor(s2, 2);
  mu = s1*(1.0f/128.f);
  rs = rsqrtf(s2*(1.0f/128.f) - mu*mu + EPS);
}

extern "C" __global__ void __launch_bounds__(512, 2)
k_attn2(const float* __restrict__ qq, const float* __restrict__ kk,
        const float* __restrict__ vv, const float* __restrict__ p,
        const float* __restrict__ U,
        const float* __restrict__ pe1, const float* __restrict__ pe2,
        const float* __restrict__ ln1g, const float* __restrict__ ln1b,
        const float* __restrict__ w1, const float* __restrict__ b1,
        const float* __restrict__ ln2g, const float* __restrict__ ln2b,
        const float* __restrict__ w2, const float* __restrict__ b2,
        float* __restrict__ xout) {
  __shared__ __align__(16) float W[8192];        // 32KB staging: pe2 / w1 half / w2 half
  __shared__ __align__(16) float p_sh[PP*4];
  __shared__ __align__(16) float pe1_sh[HID*4];
  __shared__ __align__(16) float g1s[CC], b1ls[CC], bb1[CC];
  __shared__ __align__(16) float g2s[CC], b2ls[CC], bb2[CC];
  __shared__ __align__(16) float redM[8*CC], redS[8*CC], redA[8*CC];

  const int nb = blockIdx.x;
  const int n = nb >> 7, i = nb & 127;
  const int t = threadIdx.x;
  const int wave = t >> 6;
  const int lane = t & 63;
  const int jloc = lane >> 2;
  const int q    = lane & 3;
  const int j    = wave*16 + jloc;
  const int cb   = q*32;
  const int row_i = n*PP + i;

  // ---- stage small arrays + pe2 ----
  p_sh[t] = p[n*PP*4 + (t & 511)];
  if (t < 128)              pe1_sh[t] = pe1[t];
  else if (t < 256)       { int c = t-128; g1s[c] = ln1g[c]; b1ls[c] = ln1b[c]; }
  else if (t < 384)       { int c = t-256; bb1[c] = b1[c];  g2s[c]  = ln2g[c]; }
  else                    { int c = t-384; b2ls[c] = ln2b[c]; bb2[c] = b2[c]; }
  {
    float4* W4 = (float4*)W;
    const float4* s4 = (const float4*)pe2;
    W4[t] = s4[t]; W4[t+512] = s4[t+512];      // 4096 floats
  }
  __syncthreads();

  const float pi0 = p_sh[i*4+0], pi1 = p_sh[i*4+1];
  const float pi2 = p_sh[i*4+2], pi3 = p_sh[i*4+3];
  const bool  mask_i = (pi0 == 0.0f);
  const float pd0 = pi0 - p_sh[j*4+0], pd1 = pi1 - p_sh[j*4+1];
  const float pd2 = pi2 - p_sh[j*4+2], pd3 = pi3 - p_sh[j*4+3];

  // ---- pe MLP stage 1: h0 (32 wide, 8/lane), LN over 32 via group shfl ----
  float h0[8];
  {
    float s1 = 0.f, s2 = 0.f;
    #pragma unroll
    for (int m = 0; m < 8; ++m) {
      const int u = q*8 + m;
      const float hu = pe1_sh[u*4+0]*pd0 + pe1_sh[u*4+1]*pd1
                     + pe1_sh[u*4+2]*pd2 + pe1_sh[u*4+3]*pd3;
      h0[m] = hu; s1 += hu; s2 += hu*hu;
    }
    s1 += __shfl_xor(s1, 1); s2 += __shfl_xor(s2, 1);
    s1 += __shfl_xor(s1, 2); s2 += __shfl_xor(s2, 2);
    const float mu = s1*(1.0f/HID);
    const float rs = rsqrtf(s2*(1.0f/HID) - mu*mu + EPS);
    #pragma unroll
    for (int m = 0; m < 8; ++m) h0[m] = fmaxf((h0[m]-mu)*rs, 0.f);
  }

  // ---- eqpe = relu(ln(h0 @ pe2.T)), 32 channels/lane ----
  float e[32];
  {
    float hx1[8], hx2[8], hx3[8];
    #pragma unroll
    for (int m = 0; m < 8; ++m) {
      hx1[m] = __shfl_xor(h0[m], 1);
      hx2[m] = __shfl_xor(h0[m], 2);
      hx3[m] = __shfl_xor(h0[m], 3);
    }
    const int u0 = q*8, u1 = (q^1)*8, u2 = (q^2)*8, u3 = (q^3)*8;
    #pragma unroll
    for (int m = 0; m < 32; ++m) {
      const int base = (cb+m)*HID;
      const float4* A0 = (const float4*)(W + base + u0);
      const float4* A1 = (const float4*)(W + base + u1);
      const float4* A2 = (const float4*)(W + base + u2);
      const float4* A3 = (const float4*)(W + base + u3);
      float acc;
      float4 w0 = A0[0], w1v = A0[1];
      acc  = w0.x*h0[0] + w0.y*h0[1] + w0.z*h0[2] + w0.w*h0[3]
           + w1v.x*h0[4] + w1v.y*h0[5] + w1v.z*h0[6] + w1v.w*h0[7];
      w0 = A1[0]; w1v = A1[1];
      acc += w0.x*hx1[0] + w0.y*hx1[1] + w0.z*hx1[2] + w0.w*hx1[3]
           + w1v.x*hx1[4] + w1v.y*hx1[5] + w1v.z*hx1[6] + w1v.w*hx1[7];
      w0 = A2[0]; w1v = A2[1];
      acc += w0.x*hx2[0] + w0.y*hx2[1] + w0.z*hx2[2] + w0.w*hx2[3]
           + w1v.x*hx2[4] + w1v.y*hx2[5] + w1v.z*hx2[6] + w1v.w*hx2[7];
      w0 = A3[0]; w1v = A3[1];
      acc += w0.x*hx3[0] + w0.y*hx3[1] + w0.z*hx3[2] + w0.w*hx3[3]
           + w1v.x*hx3[4] + w1v.y*hx3[5] + w1v.z*hx3[6] + w1v.w*hx3[7];
      e[m] = acc;
    }
    float mu, rs;
    ln_stats(e, mu, rs);
    #pragma unroll
    for (int m = 0; m < 32; ++m) e[m] = fmaxf((e[m]-mu)*rs, 0.f);
  }

  // ---- r_qk / xv, LN1+relu -> a ----
  float xv[32], a[32];
  {
    const float4* kp = (const float4*)(kk + row_i*CC + cb);
    const float4* qp = (const float4*)(qq + (n*PP + j)*CC + cb);
    const float4* vp = (const float4*)(vv + (n*PP + j)*CC + cb);
    const float4* Up = (const float4*)(U + ((size_t)row_i*PP + j)*CC + cb);
    #pragma unroll
    for (int k8 = 0; k8 < 8; ++k8) {
      float4 kf = kp[k8], qf = qp[k8], vf = vp[k8], Uf = Up[k8];
      float ue;
      ue = Uf.x + e[4*k8+0]; xv[4*k8+0] = vf.x + ue; a[4*k8+0] = kf.x - qf.x + ue;
      ue = Uf.y + e[4*k8+1]; xv[4*k8+1] = vf.y + ue; a[4*k8+1] = kf.y - qf.y + ue;
      ue = Uf.z + e[4*k8+2]; xv[4*k8+2] = vf.z + ue; a[4*k8+2] = kf.z - qf.z + ue;
      ue = Uf.w + e[4*k8+3]; xv[4*k8+3] = vf.w + ue; a[4*k8+3] = kf.w - qf.w + ue;
    }
    float mu, rs;
    ln_stats(a, mu, rs);
    #pragma unroll
    for (int m = 0; m < 32; ++m) {
      const int c = cb+m;
      a[m] = fmaxf((a[m]-mu)*rs*g1s[c] + b1ls[c], 0.f);
    }
  }

  __syncthreads();   // eqpe readers done: W free for w1

  // ---- GEMV1 (two halves) -> bv ----
  float bv[32];
  #pragma unroll 1
  for (int pass = 0; pass < 2; ++pass) {
    float4* W4 = (float4*)W;
    const float4* s4 = (const float4*)(w1 + pass*64*CC);
    #pragma unroll
    for (int r = 0; r < 4; ++r) W4[t + r*512] = s4[t + r*512];
    __syncthreads();
    gemv_half(W, a, bv, q, pass);
    __syncthreads();
  }

  // ---- +b1, LN2+relu (in place) ----
  {
    #pragma unroll
    for (int m = 0; m < 32; ++m) bv[m] += bb1[cb+m];
    float mu, rs;
    ln_stats(bv, mu, rs);
    #pragma unroll
    for (int m = 0; m < 32; ++m) {
      const int c = cb+m;
      bv[m] = fmaxf((bv[m]-mu)*rs*g2s[c] + b2ls[c], 0.f);
    }
  }

  // ---- GEMV2 (two halves) -> logits l ----
  float l[32];
  #pragma unroll 1
  for (int pass = 0; pass < 2; ++pass) {
    float4* W4 = (float4*)W;
    const float4* s4 = (const float4*)(w2 + pass*64*CC);
    #pragma unroll
    for (int r = 0; r < 4; ++r) W4[t + r*512] = s4[t + r*512];
    __syncthreads();
    gemv_half(W, bv, l, q, pass);
    __syncthreads();
  }
  #pragma unroll
  for (int m = 0; m < 32; ++m) {
    l[m] += bb2[cb+m];
    if (mask_i) l[m] = NEGV;
  }

  // ---- softmax over j: wave-reduce (16 j) then cross-wave via LDS ----
  #pragma unroll
  for (int m = 0; m < 32; ++m) {
    float mx = l[m];
    mx = fmaxf(mx, __shfl_xor(mx, 4));
    mx = fmaxf(mx, __shfl_xor(mx, 8));
    mx = fmaxf(mx, __shfl_xor(mx, 16));
    mx = fmaxf(mx, __shfl_xor(mx, 32));
    if (jloc == 0) redM[wave*CC + cb + m] = mx;
  }
  __syncthreads();
  #pragma unroll
  for (int m = 0; m < 32; ++m) {
    const int c = cb + m;
    float Mm = redM[c];
    #pragma unroll
    for (int w = 1; w < 8; ++w) Mm = fmaxf(Mm, redM[w*CC + c]);
    const float pv = __expf(l[m] - Mm);
    float sp = pv, ap = pv*xv[m];
    sp += __shfl_xor(sp, 4);  ap += __shfl_xor(ap, 4);
    sp += __shfl_xor(sp, 8);  ap += __shfl_xor(ap, 8);
    sp += __shfl_xor(sp, 16); ap += __shfl_xor(ap, 16);
    sp += __shfl_xor(sp, 32); ap += __shfl_xor(ap, 32);
    if (jloc == 0) { redS[wave*CC + c] = sp; redA[wave*CC + c] = ap; }
  }
  __syncthreads();
  if (t < 4) {
    #pragma unroll
    for (int m = 0; m < 32; ++m) {
      const int c = t*32 + m;
      float S = 0.f, A = 0.f;
      #pragma unroll
      for (int w = 0; w < 8; ++w) { S += redS[w*CC + c]; A += redA[w*CC + c]; }
      xout[row_i*CC + c] = A / S;
    }
  }
}

// ---------------- K3: A[r,u] / B[r,u] from e1 halves ----------------
extern "C" __global__ void __launch_bounds__(64)
k_e1(const float* __restrict__ xout, const float* __restrict__ e1,
     float* __restrict__ A, float* __restrict__ B) {
  const int row = blockIdx.x;
  const int t = threadIdx.x;
  __shared__ __align__(16) float xs[CC];
  xs[t]      = xout[row*CC + t];
  xs[t + 64] = xout[row*CC + t + 64];
  __syncthreads();
  const int u = t & 31;
  const int half = t >> 5;
  const float* er = e1 + u*257 + half*128;
  float s = 0.f;
  for (int cc2 = 0; cc2 < CC; ++cc2) s += xs[cc2]*er[cc2];
  (half ? B : A)[row*HID + u] = s;
}

// ---------------- K4: edge-MLP + LN + scalar softmax over j -> new_p -------
extern "C" __global__ void __launch_bounds__(128)
k_newp(const float* __restrict__ p, const float* __restrict__ A,
       const float* __restrict__ Bm, const float* __restrict__ e1,
       const float* __restrict__ e2, const float* __restrict__ x1,
       const float* __restrict__ x1b, const float* __restrict__ x2,
       const float* __restrict__ x2b, float* __restrict__ outp) {
  const int nb = blockIdx.x;
  const int n = nb >> 7, i = nb & 127;
  const int j = threadIdx.x;

  __shared__ __align__(16) float p_sh[PP*4];
  __shared__ __align__(16) float e2_sh[CC*HID];
  __shared__ __align__(16) float x1T_sh[CC*HID];
  __shared__ __align__(16) float Ai[HID];
  __shared__ __align__(16) float e1l[HID];
  __shared__ __align__(16) float x1bs[HID];
  __shared__ __align__(16) float x2s[HID];
  __shared__ __align__(16) float red[16];

  ((float4*)p_sh)[j] = ((const float4*)(p + n*PP*4))[j];
  for (int idx = j; idx < CC*HID; idx += PP) e2_sh[idx] = e2[idx];
  for (int idx = j; idx < CC*HID; idx += PP) {
    int u = idx >> 7, cc2 = idx & 127;
    x1T_sh[cc2*HID + u] = x1[idx];
  }
  if (j < HID) {
    Ai[j]   = A[(n*PP + i)*HID + j];
    e1l[j]  = e1[j*257 + 256];
    x1bs[j] = x1b[j];
    x2s[j]  = x2[j];
  }
  __syncthreads();

  const float pi0 = p_sh[i*4+0], pi1 = p_sh[i*4+1];
  const float pi2 = p_sh[i*4+2], pi3 = p_sh[i*4+3];
  const bool  mask_i = (pi0 == 0.0f);
  const float pij0 = pi0 - p_sh[j*4+0], pij1 = pi1 - p_sh[j*4+1];
  const float pij2 = pi2 - p_sh[j*4+2], pij3 = pi3 - p_sh[j*4+3];
  float nv = pij3*pij3 - (pij0*pij0 + pij1*pij1 + pij2*pij2);
  if (mask_i) nv = 0.f;

  float h1[HID];
  {
    const float4* B4 = (const float4*)(Bm + (n*PP + j)*HID);
    #pragma unroll
    for (int u4 = 0; u4 < 8; ++u4) {
      float4 b4 = B4[u4];
      h1[4*u4+0] = fmaxf(Ai[4*u4+0] + b4.x + e1l[4*u4+0]*nv, 0.f);
      h1[4*u4+1] = fmaxf(Ai[4*u4+1] + b4.y + e1l[4*u4+1]*nv, 0.f);
      h1[4*u4+2] = fmaxf(Ai[4*u4+2] + b4.z + e1l[4*u4+2]*nv, 0.f);
      h1[4*u4+3] = fmaxf(Ai[4*u4+3] + b4.w + e1l[4*u4+3]*nv, 0.f);
    }
  }

  float sum = 0.f, ss = 0.f;
  for (int cc2 = 0; cc2 < CC; ++cc2) {
    const float4* e4 = (const float4*)(e2_sh + cc2*HID);
    float m_ = 0.f;
    #pragma unroll
    for (int u4 = 0; u4 < 8; ++u4) {
      float4 w4 = e4[u4];
      m_ += w4.x*h1[4*u4+0] + w4.y*h1[4*u4+1] + w4.z*h1[4*u4+2] + w4.w*h1[4*u4+3];
    }
    m_ = fmaxf(m_, 0.f);
    if (mask_i) m_ = NEGV;
    sum += m_; ss += m_*m_;
  }
  const float mu = sum*(1.0f/CC);
  const float rs = rsqrtf(ss*(1.0f/CC) - mu*mu + EPS);

  float h2[HID];
  #pragma unroll
  for (int u = 0; u < HID; ++u) h2[u] = 0.f;
  for (int cc2 = 0; cc2 < CC; ++cc2) {
    const float4* e4 = (const float4*)(e2_sh + cc2*HID);
    float m_ = 0.f;
    #pragma unroll
    for (int u4 = 0; u4 < 8; ++u4) {
      float4 w4 = e4[u4];
      m_ += w4.x*h1[4*u4+0] + w4.y*h1[4*u4+1] + w4.z*h1[4*u4+2] + w4.w*h1[4*u4+3];
    }
    m_ = fmaxf(m_, 0.f);
    if (mask_i) m_ = NEGV;
    const float y = (m_ - mu)*rs;
    const float4* xr = (const float4*)(x1T_sh + cc2*HID);
    #pragma unroll
    for (int u4 = 0; u4 < 8; ++u4) {
      float4 w4 = xr[u4];
      h2[4*u4+0] += w4.x*y; h2[4*u4+1] += w4.y*y;
      h2[4*u4+2] += w4.z*y; h2[4*u4+3] += w4.w*y;
    }
  }
  float sj = x2b[0];
  #pragma unroll
  for (int u = 0; u < HID; ++u) sj += x2s[u]*fmaxf(h2[u] + x1bs[u], 0.f);
  sj = fmaxf(sj, 0.f);

  float mx = sj;
  #pragma unroll
  for (int m = 32; m; m >>= 1) mx = fmaxf(mx, __shfl_xor(mx, m));
  __syncthreads();
  if ((j & 63) == 0) red[j >> 6] = mx;
  __syncthreads();
  mx = fmaxf(red[0], red[1]);

  const float eV = __expf(sj - mx);
  float v0 = eV, v1 = eV*pij0, v2 = eV*pij1, v3 = eV*pij2, v4 = eV*pij3;
  #pragma unroll
  for (int m = 32; m; m >>= 1) {
    v0 += __shfl_xor(v0, m); v1 += __shfl_xor(v1, m); v2 += __shfl_xor(v2, m);
    v3 += __shfl_xor(v3, m); v4 += __shfl_xor(v4, m);
  }
  __syncthreads();
  if ((j & 63) == 0) {
    const int w = j >> 6;
    red[2 + w*5 + 0] = v0; red[2 + w*5 + 1] = v1; red[2 + w*5 + 2] = v2;
    red[2 + w*5 + 3] = v3; red[2 + w*5 + 4] = v4;
  }
  __syncthreads();
  v0 = red[2] + red[7];  v1 = red[3] + red[8];  v2 = red[4] + red[9];
  v3 = red[5] + red[10]; v4 = red[6] + red[11];

  float regc = 0.f;
  for (int jj = 0; jj < PP; ++jj) regc += (p_sh[jj*4] != 0.f) ? 1.f : 0.f;

  if (j < 4) {
    const float pid = p_sh[i*4 + j];
    const float num = (j == 0) ? v1 : (j == 1) ? v2 : (j == 2) ? v3 : v4;
    float val = pid + num/(v0*regc);
    if (pid == 0.f) val = 0.f;
    outp[(n*PP + i)*4 + j] = val;
  }
}

// ---------------- launcher ----------------
extern "C" void kernel_launch(void* const* d_in, const int* in_sizes, int n_in,
                              void* d_out, int out_size, void* d_ws, size_t ws_size,
                              hipStream_t stream) {
  const float* x    = (const float*)d_in[0];
  const float* p    = (const float*)d_in[1];
  const float* U    = (const float*)d_in[2];
  const float* wq   = (const float*)d_in[3];
  const float* bq   = (const float*)d_in[4];
  const float* wk   = (const float*)d_in[5];
  const float* bk   = (const float*)d_in[6];
  const float* wv   = (const float*)d_in[7];
  const float* bv   = (const float*)d_in[8];
  const float* ln1g = (const float*)d_in[9];
  const float* ln1b = (const float*)d_in[10];
  const float* w1   = (const float*)d_in[11];
  const float* b1   = (const float*)d_in[12];
  const float* ln2g = (const float*)d_in[13];
  const float* ln2b = (const float*)d_in[14];
  const float* w2   = (const float*)d_in[15];
  const float* b2   = (const float*)d_in[16];
  const float* pe1  = (const float*)d_in[17];
  const float* pe2  = (const float*)d_in[18];
  const float* e1   = (const float*)d_in[19];
  const float* e2   = (const float*)d_in[20];
  const float* x1   = (const float*)d_in[21];
  const float* x1b  = (const float*)d_in[22];
  const float* x2   = (const float*)d_in[23];
  const float* x2b  = (const float*)d_in[24];

  float* xout = (float*)d_out;
  float* outp = xout + NN*PP*CC;

  float* ws = (float*)d_ws;
  float* q  = ws;
  float* k  = q + NN*PP*CC;
  float* v  = k + NN*PP*CC;
  float* A  = v + NN*PP*CC;
  float* B  = A + NN*PP*HID;

  k_qkv <<<NN*PP, 128, 0, stream>>>(x, wq, bq, wk, bk, wv, bv, q, k, v);
  k_attn2<<<NN*PP, 512, 0, stream>>>(q, k, v, p, U, pe1, pe2, ln1g, ln1b,
                                     w1, b1, ln2g, ln2b, w2, b2, xout);
  k_e1  <<<NN*PP, 64, 0, stream>>>(xout, e1, A, B);
  k_newp<<<NN*PP, 128, 0, stream>>>(p, A, B, e1, e2, x1, x1b, x2, x2b, outp);
}

// Round 3
// 620.909 us; speedup vs baseline: 3.4098x; 2.0093x over previous
//
#include <hip/hip_runtime.h>
#include <math.h>

#define NN 16
#define PP 128
#define CIN 64
#define CC 128
#define HID 32
#define NEGV (-10000.0f)
#define EPS 1e-5f

typedef float f32x4 __attribute__((ext_vector_type(4)));
typedef int   i32x4 __attribute__((ext_vector_type(4)));
typedef unsigned int uint32;

__device__ __forceinline__ f32x4 mfma_bf16(i32x4 a, i32x4 b, f32x4 c) {
  // D(=C) += A*B, 16x16x32 bf16. A,B = 8 bf16 in 4 VGPRs each.
  asm("v_mfma_f32_16x16x32_bf16 %0, %1, %2, %0" : "+v"(c) : "v"(a), "v"(b));
  return c;
}

__device__ __forceinline__ unsigned short f2bf(float f) {  // RNE
  uint32 u = __float_as_uint(f);
  u += 0x7FFFu + ((u >> 16) & 1u);
  return (unsigned short)(u >> 16);
}
__device__ __forceinline__ float bf2f(unsigned short s) {
  return __uint_as_float(((uint32)s) << 16);
}

__device__ __forceinline__ float dot4(float4 a, float4 b) {
  return a.x*b.x + a.y*b.y + a.z*b.z + a.w*b.w;
}

// ---------------- K0: fp32 -> bf16 weight conversion (w1, w2, pe2) --------
extern "C" __global__ void __launch_bounds__(256)
k_prep(const float* __restrict__ w1, const float* __restrict__ w2,
       const float* __restrict__ pe2,
       unsigned short* __restrict__ w1b, unsigned short* __restrict__ w2b,
       unsigned short* __restrict__ pe2b) {
  const int idx = blockIdx.x*256 + threadIdx.x;           // 0..36863
  if (idx < 16384)      w1b[idx]        = f2bf(w1[idx]);
  else if (idx < 32768) w2b[idx-16384]  = f2bf(w2[idx-16384]);
  else                  pe2b[idx-32768] = f2bf(pe2[idx-32768]);
}

// ---------------- K1: q,k,v projections ----------------
extern "C" __global__ void __launch_bounds__(128)
k_qkv(const float* __restrict__ x,
      const float* __restrict__ wq, const float* __restrict__ bq,
      const float* __restrict__ wk, const float* __restrict__ bk,
      const float* __restrict__ wv, const float* __restrict__ bv,
      float* __restrict__ q, float* __restrict__ k, float* __restrict__ v) {
  const int row = blockIdx.x;
  const int c = threadIdx.x;
  __shared__ __align__(16) float xs[CIN];
  if (c < CIN) xs[c] = x[row*CIN + c];
  __syncthreads();
  const float4* wq4 = (const float4*)(wq + c*CIN);
  const float4* wk4 = (const float4*)(wk + c*CIN);
  const float4* wv4 = (const float4*)(wv + c*CIN);
  const float4* xs4 = (const float4*)xs;
  float sq = 0.f, sk = 0.f, sv = 0.f;
  #pragma unroll
  for (int d = 0; d < CIN/4; ++d) {
    float4 xv = xs4[d];
    sq += dot4(wq4[d], xv);
    sk += dot4(wk4[d], xv);
    sv += dot4(wv4[d], xv);
  }
  q[row*CC + c] = sq + bq[c];
  k[row*CC + c] = sk + bk[c];
  v[row*CC + c] = sv + bv[c];
}

// ===================== K2: MFMA fused attention ============================
// One (n,i) per block. 256 thr = 4 waves; wave w owns j-rows [32w,32w+32).
// A-frag: row=lane&15, k = 8*(lane>>4)+e (k-contiguous). C/D: col=lane&15,
// row=4*(lane>>4)+reg. All LNs and softmax partials intra-wave.
extern "C" __global__ void __launch_bounds__(256, 2)
k_attn3(const float* __restrict__ qq, const float* __restrict__ kk,
        const float* __restrict__ vv, const float* __restrict__ p,
        const float* __restrict__ U, const float* __restrict__ pe1,
        const unsigned short* __restrict__ pe2b,
        const unsigned short* __restrict__ w1b,
        const unsigned short* __restrict__ w2b,
        const float* __restrict__ ln1g, const float* __restrict__ ln1b,
        const float* __restrict__ b1,
        const float* __restrict__ ln2g, const float* __restrict__ ln2b,
        const float* __restrict__ b2, float* __restrict__ xout) {
  __shared__ __align__(16) unsigned short eS[CC*CC];   // 32KB: eqpe, then a2
  __shared__ __align__(16) unsigned short xvS[CC*CC];  // 32KB: xv (bf16)
  __shared__ __align__(16) char pool[CC*80];           // h0 (stride 80B) -> red[]
  __shared__ __align__(16) float p_sh[PP*4];
  __shared__ __align__(16) float pe1S[HID*4];
  __shared__ __align__(16) float kiS[CC], g1S[CC], b1lS[CC], bb1S[CC];
  __shared__ __align__(16) float g2S[CC], b2lS[CC], bb2S[CC];

  const int nb = blockIdx.x;
  const int n = nb >> 7, ii = nb & 127;
  const int t = threadIdx.x;
  const int lane = t & 63;
  const int wave = t >> 6;
  const int l15 = lane & 15;
  const int g4  = lane >> 4;
  const int jb  = wave * 32;

  // ---- stage ----
  p_sh[t]     = p[n*PP*4 + t];
  p_sh[t+256] = p[n*PP*4 + t + 256];
  {
    const int c = t & 127;
    if (t < 128) {
      kiS[c] = kk[nb*CC + c];
      g1S[c] = ln1g[c]; b1lS[c] = ln1b[c]; bb1S[c] = b1[c];
      pe1S[c] = pe1[c];
    } else {
      g2S[c] = ln2g[c]; b2lS[c] = ln2b[c]; bb2S[c] = b2[c];
    }
  }
  __syncthreads();

  const bool mask_i = (p_sh[ii*4] == 0.0f);

  // ---- h0 = relu(ln(pij @ pe1.T)) : thread t -> (j = t>>1, 16 u's) ----
  {
    const int j  = t >> 1;
    const int uh = (t & 1) * 16;
    const float pd0 = p_sh[ii*4+0] - p_sh[j*4+0];
    const float pd1 = p_sh[ii*4+1] - p_sh[j*4+1];
    const float pd2 = p_sh[ii*4+2] - p_sh[j*4+2];
    const float pd3 = p_sh[ii*4+3] - p_sh[j*4+3];
    float hv[16]; float s1 = 0.f, s2 = 0.f;
    #pragma unroll
    for (int u = 0; u < 16; ++u) {
      const int uu = uh + u;
      const float h = pe1S[uu*4+0]*pd0 + pe1S[uu*4+1]*pd1
                    + pe1S[uu*4+2]*pd2 + pe1S[uu*4+3]*pd3;
      hv[u] = h; s1 += h; s2 += h*h;
    }
    s1 += __shfl_xor(s1, 1); s2 += __shfl_xor(s2, 1);
    const float mu = s1*(1.f/HID);
    const float rs = rsqrtf(s2*(1.f/HID) - mu*mu + EPS);
    uint32 pk[8];
    #pragma unroll
    for (int u2 = 0; u2 < 8; ++u2) {
      const float a0 = fmaxf((hv[2*u2+0]-mu)*rs, 0.f);
      const float a1 = fmaxf((hv[2*u2+1]-mu)*rs, 0.f);
      pk[u2] = (uint32)f2bf(a0) | ((uint32)f2bf(a1) << 16);
    }
    i32x4* dst = (i32x4*)(pool + j*80 + uh*2);   // row stride 40 bf16 = 80B
    dst[0] = (i32x4){(int)pk[0],(int)pk[1],(int)pk[2],(int)pk[3]};
    dst[1] = (i32x4){(int)pk[4],(int)pk[5],(int)pk[6],(int)pk[7]};
  }
  // no barrier: each wave wrote and reads only its own 32 rows

  // ---- GEMM0: E = h0 @ pe2^T (K=32, one mfma per tile) ----
  f32x4 accE[2][8];
  {
    i32x4 A0[2];
    #pragma unroll
    for (int mt = 0; mt < 2; ++mt) {
      const int j = jb + mt*16 + l15;
      A0[mt] = *(const i32x4*)(pool + j*80 + g4*16);
    }
    #pragma unroll
    for (int nt = 0; nt < 8; ++nt) {
      const int co = nt*16 + l15;
      const i32x4 B = *(const i32x4*)(pe2b + co*HID + g4*8);
      #pragma unroll
      for (int mt = 0; mt < 2; ++mt) {
        f32x4 z = {0.f,0.f,0.f,0.f};
        accE[mt][nt] = mfma_bf16(A0[mt], B, z);
      }
    }
  }

  // ---- LN(E)+relu -> eS (bf16, XOR-swizzled) ----
  #pragma unroll
  for (int mt = 0; mt < 2; ++mt) {
    float mu[4], rsv[4];
    #pragma unroll
    for (int r = 0; r < 4; ++r) {
      float a = 0.f, b = 0.f;
      #pragma unroll
      for (int nt = 0; nt < 8; ++nt) { const float v = accE[mt][nt][r]; a += v; b += v*v; }
      a += __shfl_xor(a, 1); b += __shfl_xor(b, 1);
      a += __shfl_xor(a, 2); b += __shfl_xor(b, 2);
      a += __shfl_xor(a, 4); b += __shfl_xor(b, 4);
      a += __shfl_xor(a, 8); b += __shfl_xor(b, 8);
      mu[r]  = a*(1.f/CC);
      rsv[r] = rsqrtf(b*(1.f/CC) - mu[r]*mu[r] + EPS);
    }
    #pragma unroll
    for (int nt = 0; nt < 8; ++nt) {
      const int co = nt*16 + l15;
      #pragma unroll
      for (int r = 0; r < 4; ++r) {
        const int jr = jb + mt*16 + g4*4 + r;
        const float e = fmaxf((accE[mt][nt][r]-mu[r])*rsv[r], 0.f);
        eS[jr*CC + (co ^ ((jr&7)<<3))] = f2bf(e);
      }
    }
  }

  // ---- r_qk / xv / LN1+relu -> A1 frags (regs); xv -> xvS ----
  i32x4 A1[2][4];
  #pragma unroll
  for (int mt = 0; mt < 2; ++mt) {
    const int j = jb + mt*16 + l15;
    float r8[4][8];
    float s1 = 0.f, s2 = 0.f;
    #pragma unroll
    for (int ks = 0; ks < 4; ++ks) {
      const int c0 = ks*32 + g4*8;
      const float* Up = U + ((size_t)nb*PP + j)*CC + c0;
      const float* qp = qq + (n*PP + j)*CC + c0;
      const float* vp = vv + (n*PP + j)*CC + c0;
      const f32x4 u0 = *(const f32x4*)(Up),    u1 = *(const f32x4*)(Up+4);
      const f32x4 q0 = *(const f32x4*)(qp),    q1 = *(const f32x4*)(qp+4);
      const f32x4 v0 = *(const f32x4*)(vp),    v1 = *(const f32x4*)(vp+4);
      const f32x4 k0 = *(const f32x4*)(kiS+c0), k1 = *(const f32x4*)(kiS+c0+4);
      const i32x4 ep = *(const i32x4*)(eS + j*CC + (c0 ^ ((j&7)<<3)));
      float Uf[8], Qf[8], Vf[8], Kf[8], Ef[8];
      #pragma unroll
      for (int e_ = 0; e_ < 4; ++e_) {
        Uf[e_] = u0[e_]; Uf[e_+4] = u1[e_];
        Qf[e_] = q0[e_]; Qf[e_+4] = q1[e_];
        Vf[e_] = v0[e_]; Vf[e_+4] = v1[e_];
        Kf[e_] = k0[e_]; Kf[e_+4] = k1[e_];
      }
      #pragma unroll
      for (int w_ = 0; w_ < 4; ++w_) {
        const uint32 eu = (uint32)ep[w_];
        Ef[2*w_]   = bf2f((unsigned short)(eu & 0xFFFFu));
        Ef[2*w_+1] = bf2f((unsigned short)(eu >> 16));
      }
      uint32 xw[4];
      #pragma unroll
      for (int w_ = 0; w_ < 4; ++w_) {
        const float xa = Vf[2*w_]   + Uf[2*w_]   + Ef[2*w_];
        const float xb = Vf[2*w_+1] + Uf[2*w_+1] + Ef[2*w_+1];
        xw[w_] = (uint32)f2bf(xa) | ((uint32)f2bf(xb) << 16);
      }
      *(i32x4*)(xvS + j*CC + (c0 ^ ((j&7)<<3))) =
          (i32x4){(int)xw[0],(int)xw[1],(int)xw[2],(int)xw[3]};
      #pragma unroll
      for (int e_ = 0; e_ < 8; ++e_) {
        const float rv = Kf[e_] - Qf[e_] + Uf[e_] + Ef[e_];
        r8[ks][e_] = rv; s1 += rv; s2 += rv*rv;
      }
    }
    s1 += __shfl_xor(s1, 16); s2 += __shfl_xor(s2, 16);
    s1 += __shfl_xor(s1, 32); s2 += __shfl_xor(s2, 32);
    const float mu = s1*(1.f/CC);
    const float rs = rsqrtf(s2*(1.f/CC) - mu*mu + EPS);
    #pragma unroll
    for (int ks = 0; ks < 4; ++ks) {
      const int c0 = ks*32 + g4*8;
      const f32x4 ga = *(const f32x4*)(g1S + c0), gb = *(const f32x4*)(g1S + c0 + 4);
      const f32x4 ba = *(const f32x4*)(b1lS + c0), bbv = *(const f32x4*)(b1lS + c0 + 4);
      uint32 pk[4];
      #pragma unroll
      for (int w_ = 0; w_ < 4; ++w_) {
        const int eA = 2*w_, eB = 2*w_+1;
        const float gA = (eA<4)?ga[eA]:gb[eA-4], gB = (eB<4)?ga[eB]:gb[eB-4];
        const float bA = (eA<4)?ba[eA]:bbv[eA-4], bB = (eB<4)?ba[eB]:bbv[eB-4];
        const float aA = fmaxf((r8[ks][eA]-mu)*rs*gA + bA, 0.f);
        const float aB = fmaxf((r8[ks][eB]-mu)*rs*gB + bB, 0.f);
        pk[w_] = (uint32)f2bf(aA) | ((uint32)f2bf(aB) << 16);
      }
      A1[mt][ks] = (i32x4){(int)pk[0],(int)pk[1],(int)pk[2],(int)pk[3]};
    }
  }

  // ---- GEMM1: acc1 = a @ w1^T ----
  f32x4 acc1[2][8];
  #pragma unroll
  for (int mt = 0; mt < 2; ++mt)
    #pragma unroll
    for (int nt = 0; nt < 8; ++nt) acc1[mt][nt] = (f32x4){0.f,0.f,0.f,0.f};
  #pragma unroll
  for (int ks = 0; ks < 4; ++ks) {
    #pragma unroll
    for (int nt = 0; nt < 8; ++nt) {
      const int co = nt*16 + l15;
      const i32x4 B = *(const i32x4*)(w1b + co*CC + ks*32 + g4*8);
      acc1[0][nt] = mfma_bf16(A1[0][ks], B, acc1[0][nt]);
      acc1[1][nt] = mfma_bf16(A1[1][ks], B, acc1[1][nt]);
    }
  }

  // ---- +b1, LN2+relu -> a2 (eS reused), read back A2 frags ----
  #pragma unroll
  for (int mt = 0; mt < 2; ++mt) {
    float mu[4], rsv[4];
    #pragma unroll
    for (int r = 0; r < 4; ++r) {
      float a = 0.f, b = 0.f;
      #pragma unroll
      for (int nt = 0; nt < 8; ++nt) {
        const float v = acc1[mt][nt][r] + bb1S[nt*16 + l15];
        acc1[mt][nt][r] = v;
        a += v; b += v*v;
      }
      a += __shfl_xor(a, 1); b += __shfl_xor(b, 1);
      a += __shfl_xor(a, 2); b += __shfl_xor(b, 2);
      a += __shfl_xor(a, 4); b += __shfl_xor(b, 4);
      a += __shfl_xor(a, 8); b += __shfl_xor(b, 8);
      mu[r]  = a*(1.f/CC);
      rsv[r] = rsqrtf(b*(1.f/CC) - mu[r]*mu[r] + EPS);
    }
    #pragma unroll
    for (int nt = 0; nt < 8; ++nt) {
      const int co = nt*16 + l15;
      const float g2v = g2S[co], b2v = b2lS[co];
      #pragma unroll
      for (int r = 0; r < 4; ++r) {
        const int jr = jb + mt*16 + g4*4 + r;
        const float a2 = fmaxf((acc1[mt][nt][r]-mu[r])*rsv[r]*g2v + b2v, 0.f);
        eS[jr*CC + (co ^ ((jr&7)<<3))] = f2bf(a2);
      }
    }
  }
  i32x4 A2[2][4];
  #pragma unroll
  for (int mt = 0; mt < 2; ++mt) {
    const int j = jb + mt*16 + l15;
    #pragma unroll
    for (int ks = 0; ks < 4; ++ks) {
      const int c0 = ks*32 + g4*8;
      A2[mt][ks] = *(const i32x4*)(eS + j*CC + (c0 ^ ((j&7)<<3)));
    }
  }

  // ---- GEMM2: logits = a2 @ w2^T ----
  f32x4 acc2[2][8];
  #pragma unroll
  for (int mt = 0; mt < 2; ++mt)
    #pragma unroll
    for (int nt = 0; nt < 8; ++nt) acc2[mt][nt] = (f32x4){0.f,0.f,0.f,0.f};
  #pragma unroll
  for (int ks = 0; ks < 4; ++ks) {
    #pragma unroll
    for (int nt = 0; nt < 8; ++nt) {
      const int co = nt*16 + l15;
      const i32x4 B = *(const i32x4*)(w2b + co*CC + ks*32 + g4*8);
      acc2[0][nt] = mfma_bf16(A2[0][ks], B, acc2[0][nt]);
      acc2[1][nt] = mfma_bf16(A2[1][ks], B, acc2[1][nt]);
    }
  }

  // ---- softmax over j (cross-wave via red[] in pool) + x_out ----
  float* redM = (float*)pool;          // 512 f
  float* redS = redM + 512;            // 512 f
  float* redA = redM + 1024;           // 512 f
  __syncthreads();                     // all h0S/pool reads done
  #pragma unroll
  for (int nt = 0; nt < 8; ++nt) {
    const int co = nt*16 + l15;
    const float b2v = bb2S[co];
    float m = -INFINITY;
    #pragma unroll
    for (int mt = 0; mt < 2; ++mt)
      #pragma unroll
      for (int r = 0; r < 4; ++r) {
        float lv = acc2[mt][nt][r] + b2v;
        if (mask_i) lv = NEGV;
        acc2[mt][nt][r] = lv;
        m = fmaxf(m, lv);
      }
    m = fmaxf(m, __shfl_xor(m, 16));
    m = fmaxf(m, __shfl_xor(m, 32));
    if (g4 == 0) redM[wave*CC + co] = m;
  }
  __syncthreads();
  #pragma unroll
  for (int nt = 0; nt < 8; ++nt) {
    const int co = nt*16 + l15;
    const float M = fmaxf(fmaxf(redM[co], redM[CC+co]),
                          fmaxf(redM[2*CC+co], redM[3*CC+co]));
    float S = 0.f, A = 0.f;
    #pragma unroll
    for (int mt = 0; mt < 2; ++mt)
      #pragma unroll
      for (int r = 0; r < 4; ++r) {
        const int jr = jb + mt*16 + g4*4 + r;
        const float pv = __expf(acc2[mt][nt][r] - M);
        const float xvv = bf2f(xvS[jr*CC + (co ^ ((jr&7)<<3))]);
        S += pv; A += pv*xvv;
      }
    S += __shfl_xor(S, 16); A += __shfl_xor(A, 16);
    S += __shfl_xor(S, 32); A += __shfl_xor(A, 32);
    if (g4 == 0) { redS[wave*CC + co] = S; redA[wave*CC + co] = A; }
  }
  __syncthreads();
  if (t < CC) {
    const float S = redS[t] + redS[CC+t] + redS[2*CC+t] + redS[3*CC+t];
    const float A = redA[t] + redA[CC+t] + redA[2*CC+t] + redA[3*CC+t];
    xout[nb*CC + t] = A / S;
  }
}

// ---------------- K3: A[r,u] / B[r,u] from e1 halves ----------------
extern "C" __global__ void __launch_bounds__(64)
k_e1(const float* __restrict__ xout, const float* __restrict__ e1,
     float* __restrict__ A, float* __restrict__ B) {
  const int row = blockIdx.x;
  const int t = threadIdx.x;
  __shared__ __align__(16) float xs[CC];
  xs[t]      = xout[row*CC + t];
  xs[t + 64] = xout[row*CC + t + 64];
  __syncthreads();
  const int u = t & 31;
  const int half = t >> 5;
  const float* er = e1 + u*257 + half*128;
  float s = 0.f;
  for (int cc2 = 0; cc2 < CC; ++cc2) s += xs[cc2]*er[cc2];
  (half ? B : A)[row*HID + u] = s;
}

// ---------------- K4: edge-MLP + LN + scalar softmax over j -> new_p -------
extern "C" __global__ void __launch_bounds__(128)
k_newp(const float* __restrict__ p, const float* __restrict__ A,
       const float* __restrict__ Bm, const float* __restrict__ e1,
       const float* __restrict__ e2, const float* __restrict__ x1,
       const float* __restrict__ x1b, const float* __restrict__ x2,
       const float* __restrict__ x2b, float* __restrict__ outp) {
  const int nb = blockIdx.x;
  const int n = nb >> 7, i = nb & 127;
  const int j = threadIdx.x;

  __shared__ __align__(16) float p_sh[PP*4];
  __shared__ __align__(16) float e2_sh[CC*HID];
  __shared__ __align__(16) float x1T_sh[CC*HID];
  __shared__ __align__(16) float Ai[HID];
  __shared__ __align__(16) float e1l[HID];
  __shared__ __align__(16) float x1bs[HID];
  __shared__ __align__(16) float x2s[HID];
  __shared__ __align__(16) float red[16];

  ((float4*)p_sh)[j] = ((const float4*)(p + n*PP*4))[j];
  for (int idx = j; idx < CC*HID; idx += PP) e2_sh[idx] = e2[idx];
  for (int idx = j; idx < CC*HID; idx += PP) {
    int u = idx >> 7, cc2 = idx & 127;
    x1T_sh[cc2*HID + u] = x1[idx];
  }
  if (j < HID) {
    Ai[j]   = A[(n*PP + i)*HID + j];
    e1l[j]  = e1[j*257 + 256];
    x1bs[j] = x1b[j];
    x2s[j]  = x2[j];
  }
  __syncthreads();

  const float pi0 = p_sh[i*4+0], pi1 = p_sh[i*4+1];
  const float pi2 = p_sh[i*4+2], pi3 = p_sh[i*4+3];
  const bool  mask_i = (pi0 == 0.0f);
  const float pij0 = pi0 - p_sh[j*4+0], pij1 = pi1 - p_sh[j*4+1];
  const float pij2 = pi2 - p_sh[j*4+2], pij3 = pi3 - p_sh[j*4+3];
  float nv = pij3*pij3 - (pij0*pij0 + pij1*pij1 + pij2*pij2);
  if (mask_i) nv = 0.f;

  float h1[HID];
  {
    const float4* B4 = (const float4*)(Bm + (n*PP + j)*HID);
    #pragma unroll
    for (int u4 = 0; u4 < 8; ++u4) {
      float4 b4 = B4[u4];
      h1[4*u4+0] = fmaxf(Ai[4*u4+0] + b4.x + e1l[4*u4+0]*nv, 0.f);
      h1[4*u4+1] = fmaxf(Ai[4*u4+1] + b4.y + e1l[4*u4+1]*nv, 0.f);
      h1[4*u4+2] = fmaxf(Ai[4*u4+2] + b4.z + e1l[4*u4+2]*nv, 0.f);
      h1[4*u4+3] = fmaxf(Ai[4*u4+3] + b4.w + e1l[4*u4+3]*nv, 0.f);
    }
  }

  float sum = 0.f, ss = 0.f;
  for (int cc2 = 0; cc2 < CC; ++cc2) {
    const float4* e4 = (const float4*)(e2_sh + cc2*HID);
    float m_ = 0.f;
    #pragma unroll
    for (int u4 = 0; u4 < 8; ++u4) {
      float4 w4 = e4[u4];
      m_ += w4.x*h1[4*u4+0] + w4.y*h1[4*u4+1] + w4.z*h1[4*u4+2] + w4.w*h1[4*u4+3];
    }
    m_ = fmaxf(m_, 0.f);
    if (mask_i) m_ = NEGV;
    sum += m_; ss += m_*m_;
  }
  const float mu = sum*(1.0f/CC);
  const float rs = rsqrtf(ss*(1.0f/CC) - mu*mu + EPS);

  float h2[HID];
  #pragma unroll
  for (int u = 0; u < HID; ++u) h2[u] = 0.f;
  for (int cc2 = 0; cc2 < CC; ++cc2) {
    const float4* e4 = (const float4*)(e2_sh + cc2*HID);
    float m_ = 0.f;
    #pragma unroll
    for (int u4 = 0; u4 < 8; ++u4) {
      float4 w4 = e4[u4];
      m_ += w4.x*h1[4*u4+0] + w4.y*h1[4*u4+1] + w4.z*h1[4*u4+2] + w4.w*h1[4*u4+3];
    }
    m_ = fmaxf(m_, 0.f);
    if (mask_i) m_ = NEGV;
    const float y = (m_ - mu)*rs;
    const float4* xr = (const float4*)(x1T_sh + cc2*HID);
    #pragma unroll
    for (int u4 = 0; u4 < 8; ++u4) {
      float4 w4 = xr[u4];
      h2[4*u4+0] += w4.x*y; h2[4*u4+1] += w4.y*y;
      h2[4*u4+2] += w4.z*y; h2[4*u4+3] += w4.w*y;
    }
  }
  float sj = x2b[0];
  #pragma unroll
  for (int u = 0; u < HID; ++u) sj += x2s[u]*fmaxf(h2[u] + x1bs[u], 0.f);
  sj = fmaxf(sj, 0.f);

  float mx = sj;
  #pragma unroll
  for (int m = 32; m; m >>= 1) mx = fmaxf(mx, __shfl_xor(mx, m));
  __syncthreads();
  if ((j & 63) == 0) red[j >> 6] = mx;
  __syncthreads();
  mx = fmaxf(red[0], red[1]);

  const float eV = __expf(sj - mx);
  float v0 = eV, v1 = eV*pij0, v2 = eV*pij1, v3 = eV*pij2, v4 = eV*pij3;
  #pragma unroll
  for (int m = 32; m; m >>= 1) {
    v0 += __shfl_xor(v0, m); v1 += __shfl_xor(v1, m); v2 += __shfl_xor(v2, m);
    v3 += __shfl_xor(v3, m); v4 += __shfl_xor(v4, m);
  }
  __syncthreads();
  if ((j & 63) == 0) {
    const int w = j >> 6;
    red[2 + w*5 + 0] = v0; red[2 + w*5 + 1] = v1; red[2 + w*5 + 2] = v2;
    red[2 + w*5 + 3] = v3; red[2 + w*5 + 4] = v4;
  }
  __syncthreads();
  v0 = red[2] + red[7];  v1 = red[3] + red[8];  v2 = red[4] + red[9];
  v3 = red[5] + red[10]; v4 = red[6] + red[11];

  float regc = 0.f;
  for (int jj = 0; jj < PP; ++jj) regc += (p_sh[jj*4] != 0.f) ? 1.f : 0.f;

  if (j < 4) {
    const float pid = p_sh[i*4 + j];
    const float num = (j == 0) ? v1 : (j == 1) ? v2 : (j == 2) ? v3 : v4;
    float val = pid + num/(v0*regc);
    if (pid == 0.f) val = 0.f;
    outp[(n*PP + i)*4 + j] = val;
  }
}

// ---------------- launcher ----------------
extern "C" void kernel_launch(void* const* d_in, const int* in_sizes, int n_in,
                              void* d_out, int out_size, void* d_ws, size_t ws_size,
                              hipStream_t stream) {
  const float* x    = (const float*)d_in[0];
  const float* p    = (const float*)d_in[1];
  const float* U    = (const float*)d_in[2];
  const float* wq   = (const float*)d_in[3];
  const float* bq   = (const float*)d_in[4];
  const float* wk   = (const float*)d_in[5];
  const float* bk   = (const float*)d_in[6];
  const float* wv   = (const float*)d_in[7];
  const float* bv   = (const float*)d_in[8];
  const float* ln1g = (const float*)d_in[9];
  const float* ln1b = (const float*)d_in[10];
  const float* w1   = (const float*)d_in[11];
  const float* b1   = (const float*)d_in[12];
  const float* ln2g = (const float*)d_in[13];
  const float* ln2b = (const float*)d_in[14];
  const float* w2   = (const float*)d_in[15];
  const float* b2   = (const float*)d_in[16];
  const float* pe1  = (const float*)d_in[17];
  const float* pe2  = (const float*)d_in[18];
  const float* e1   = (const float*)d_in[19];
  const float* e2   = (const float*)d_in[20];
  const float* x1   = (const float*)d_in[21];
  const float* x1b  = (const float*)d_in[22];
  const float* x2   = (const float*)d_in[23];
  const float* x2b  = (const float*)d_in[24];

  float* xout = (float*)d_out;
  float* outp = xout + NN*PP*CC;

  float* ws = (float*)d_ws;
  float* q  = ws;                       // 262144
  float* k  = q + NN*PP*CC;             // 262144
  float* v  = k + NN*PP*CC;             // 262144
  float* A  = v + NN*PP*CC;             // 65536
  float* B  = A + NN*PP*HID;            // 65536
  unsigned short* wsb  = (unsigned short*)(B + NN*PP*HID);
  unsigned short* w1b  = wsb;           // 16384 bf16
  unsigned short* w2b  = wsb + 16384;   // 16384 bf16
  unsigned short* pe2b = wsb + 32768;   // 4096 bf16

  k_prep<<<144, 256, 0, stream>>>(w1, w2, pe2, w1b, w2b, pe2b);
  k_qkv <<<NN*PP, 128, 0, stream>>>(x, wq, bq, wk, bk, wv, bv, q, k, v);
  k_attn3<<<NN*PP, 256, 0, stream>>>(q, k, v, p, U, pe1, pe2b, w1b, w2b,
                                     ln1g, ln1b, b1, ln2g, ln2b, b2, xout);
  k_e1  <<<NN*PP, 64, 0, stream>>>(xout, e1, A, B);
  k_newp<<<NN*PP, 128, 0, stream>>>(p, A, B, e1, e2, x1, x1b, x2, x2b, outp);
}

// Round 5
// 468.925 us; speedup vs baseline: 4.5150x; 1.3241x over previous
//
#include <hip/hip_runtime.h>
#include <math.h>

#define NN 16
#define PP 128
#define CIN 64
#define CC 128
#define HID 32
#define NEGV (-10000.0f)
#define EPS 1e-5f

typedef float f32x4 __attribute__((ext_vector_type(4)));
typedef int   i32x4 __attribute__((ext_vector_type(4)));
typedef unsigned int uint32;

__device__ __forceinline__ f32x4 mfma_bf16(i32x4 a, i32x4 b, f32x4 c) {
  // D(=C) += A*B, 16x16x32 bf16. A,B = 8 bf16 in 4 VGPRs each.
  asm("v_mfma_f32_16x16x32_bf16 %0, %1, %2, %0" : "+v"(c) : "v"(a), "v"(b));
  return c;
}

__device__ __forceinline__ unsigned short f2bf(float f) {  // RNE
  uint32 u = __float_as_uint(f);
  u += 0x7FFFu + ((u >> 16) & 1u);
  return (unsigned short)(u >> 16);
}
__device__ __forceinline__ float bf2f(unsigned short s) {
  return __uint_as_float(((uint32)s) << 16);
}
__device__ __forceinline__ float dot4(float4 a, float4 b) {
  return a.x*b.x + a.y*b.y + a.z*b.z + a.w*b.w;
}

// ---------------- K0: fp32 -> bf16 weight conversion ----------------------
extern "C" __global__ void __launch_bounds__(256)
k_prep(const float* __restrict__ w1, const float* __restrict__ w2,
       const float* __restrict__ pe2, const float* __restrict__ e2,
       const float* __restrict__ x1,
       unsigned short* __restrict__ w1b, unsigned short* __restrict__ w2b,
       unsigned short* __restrict__ pe2b, unsigned short* __restrict__ e2b,
       unsigned short* __restrict__ x1bb) {
  const int idx = blockIdx.x*256 + threadIdx.x;           // 0..45055
  if (idx < 16384)      w1b[idx]        = f2bf(w1[idx]);
  else if (idx < 32768) w2b[idx-16384]  = f2bf(w2[idx-16384]);
  else if (idx < 36864) pe2b[idx-32768] = f2bf(pe2[idx-32768]);
  else if (idx < 40960) e2b[idx-36864]  = f2bf(e2[idx-36864]);
  else if (idx < 45056) x1bb[idx-40960] = f2bf(x1[idx-40960]);
}

// ---------------- K1: q,k,v projections ----------------
extern "C" __global__ void __launch_bounds__(128)
k_qkv(const float* __restrict__ x,
      const float* __restrict__ wq, const float* __restrict__ bq,
      const float* __restrict__ wk, const float* __restrict__ bk,
      const float* __restrict__ wv, const float* __restrict__ bv,
      float* __restrict__ q, float* __restrict__ k, float* __restrict__ v) {
  const int row = blockIdx.x;
  const int c = threadIdx.x;
  __shared__ __align__(16) float xs[CIN];
  if (c < CIN) xs[c] = x[row*CIN + c];
  __syncthreads();
  const float4* wq4 = (const float4*)(wq + c*CIN);
  const float4* wk4 = (const float4*)(wk + c*CIN);
  const float4* wv4 = (const float4*)(wv + c*CIN);
  const float4* xs4 = (const float4*)xs;
  float sq = 0.f, sk = 0.f, sv = 0.f;
  #pragma unroll
  for (int d = 0; d < CIN/4; ++d) {
    float4 xv = xs4[d];
    sq += dot4(wq4[d], xv);
    sk += dot4(wk4[d], xv);
    sv += dot4(wv4[d], xv);
  }
  q[row*CC + c] = sq + bq[c];
  k[row*CC + c] = sk + bk[c];
  v[row*CC + c] = sv + bv[c];
}

// ===================== K2: MFMA fused attention (R3-proven) ================
// One (n,i) per block. 256 thr = 4 waves; wave w owns j-rows [32w,32w+32).
// A-frag: row=lane&15, k = 8*(lane>>4)+e (k-contiguous). C/D: col=lane&15,
// row=4*(lane>>4)+reg. All LNs and softmax partials intra-wave.
extern "C" __global__ void __launch_bounds__(256, 2)
k_attn3(const float* __restrict__ qq, const float* __restrict__ kk,
        const float* __restrict__ vv, const float* __restrict__ p,
        const float* __restrict__ U, const float* __restrict__ pe1,
        const unsigned short* __restrict__ pe2b,
        const unsigned short* __restrict__ w1b,
        const unsigned short* __restrict__ w2b,
        const float* __restrict__ ln1g, const float* __restrict__ ln1b,
        const float* __restrict__ b1,
        const float* __restrict__ ln2g, const float* __restrict__ ln2b,
        const float* __restrict__ b2, float* __restrict__ xout) {
  __shared__ __align__(16) unsigned short eS[CC*CC];   // 32KB: eqpe, then a2
  __shared__ __align__(16) unsigned short xvS[CC*CC];  // 32KB: xv (bf16)
  __shared__ __align__(16) char pool[CC*80];           // h0 (stride 80B) -> red[]
  __shared__ __align__(16) float p_sh[PP*4];
  __shared__ __align__(16) float pe1S[HID*4];
  __shared__ __align__(16) float kiS[CC], g1S[CC], b1lS[CC], bb1S[CC];
  __shared__ __align__(16) float g2S[CC], b2lS[CC], bb2S[CC];

  const int nb = blockIdx.x;
  const int n = nb >> 7, ii = nb & 127;
  const int t = threadIdx.x;
  const int lane = t & 63;
  const int wave = t >> 6;
  const int l15 = lane & 15;
  const int g4  = lane >> 4;
  const int jb  = wave * 32;

  // ---- stage ----
  p_sh[t]     = p[n*PP*4 + t];
  p_sh[t+256] = p[n*PP*4 + t + 256];
  {
    const int c = t & 127;
    if (t < 128) {
      kiS[c] = kk[nb*CC + c];
      g1S[c] = ln1g[c]; b1lS[c] = ln1b[c]; bb1S[c] = b1[c];
      pe1S[c] = pe1[c];
    } else {
      g2S[c] = ln2g[c]; b2lS[c] = ln2b[c]; bb2S[c] = b2[c];
    }
  }
  __syncthreads();

  const bool mask_i = (p_sh[ii*4] == 0.0f);

  // ---- h0 = relu(ln(pij @ pe1.T)) : thread t -> (j = t>>1, 16 u's) ----
  {
    const int j  = t >> 1;
    const int uh = (t & 1) * 16;
    const float pd0 = p_sh[ii*4+0] - p_sh[j*4+0];
    const float pd1 = p_sh[ii*4+1] - p_sh[j*4+1];
    const float pd2 = p_sh[ii*4+2] - p_sh[j*4+2];
    const float pd3 = p_sh[ii*4+3] - p_sh[j*4+3];
    float hv[16]; float s1 = 0.f, s2 = 0.f;
    #pragma unroll
    for (int u = 0; u < 16; ++u) {
      const int uu = uh + u;
      const float h = pe1S[uu*4+0]*pd0 + pe1S[uu*4+1]*pd1
                    + pe1S[uu*4+2]*pd2 + pe1S[uu*4+3]*pd3;
      hv[u] = h; s1 += h; s2 += h*h;
    }
    s1 += __shfl_xor(s1, 1); s2 += __shfl_xor(s2, 1);
    const float mu = s1*(1.f/HID);
    const float rs = rsqrtf(s2*(1.f/HID) - mu*mu + EPS);
    uint32 pk[8];
    #pragma unroll
    for (int u2 = 0; u2 < 8; ++u2) {
      const float a0 = fmaxf((hv[2*u2+0]-mu)*rs, 0.f);
      const float a1 = fmaxf((hv[2*u2+1]-mu)*rs, 0.f);
      pk[u2] = (uint32)f2bf(a0) | ((uint32)f2bf(a1) << 16);
    }
    i32x4* dst = (i32x4*)(pool + j*80 + uh*2);   // row stride 40 bf16 = 80B
    dst[0] = (i32x4){(int)pk[0],(int)pk[1],(int)pk[2],(int)pk[3]};
    dst[1] = (i32x4){(int)pk[4],(int)pk[5],(int)pk[6],(int)pk[7]};
  }
  // no barrier: each wave wrote and reads only its own 32 rows

  // ---- GEMM0: E = h0 @ pe2^T (K=32, one mfma per tile) ----
  f32x4 accE[2][8];
  {
    i32x4 A0[2];
    #pragma unroll
    for (int mt = 0; mt < 2; ++mt) {
      const int j = jb + mt*16 + l15;
      A0[mt] = *(const i32x4*)(pool + j*80 + g4*16);
    }
    #pragma unroll
    for (int nt = 0; nt < 8; ++nt) {
      const int co = nt*16 + l15;
      const i32x4 B = *(const i32x4*)(pe2b + co*HID + g4*8);
      #pragma unroll
      for (int mt = 0; mt < 2; ++mt) {
        f32x4 z = {0.f,0.f,0.f,0.f};
        accE[mt][nt] = mfma_bf16(A0[mt], B, z);
      }
    }
  }

  // ---- LN(E)+relu -> eS (bf16, XOR-swizzled) ----
  #pragma unroll
  for (int mt = 0; mt < 2; ++mt) {
    float mu[4], rsv[4];
    #pragma unroll
    for (int r = 0; r < 4; ++r) {
      float a = 0.f, b = 0.f;
      #pragma unroll
      for (int nt = 0; nt < 8; ++nt) { const float v = accE[mt][nt][r]; a += v; b += v*v; }
      a += __shfl_xor(a, 1); b += __shfl_xor(b, 1);
      a += __shfl_xor(a, 2); b += __shfl_xor(b, 2);
      a += __shfl_xor(a, 4); b += __shfl_xor(b, 4);
      a += __shfl_xor(a, 8); b += __shfl_xor(b, 8);
      mu[r]  = a*(1.f/CC);
      rsv[r] = rsqrtf(b*(1.f/CC) - mu[r]*mu[r] + EPS);
    }
    #pragma unroll
    for (int nt = 0; nt < 8; ++nt) {
      const int co = nt*16 + l15;
      #pragma unroll
      for (int r = 0; r < 4; ++r) {
        const int jr = jb + mt*16 + g4*4 + r;
        const float e = fmaxf((accE[mt][nt][r]-mu[r])*rsv[r], 0.f);
        eS[jr*CC + (co ^ ((jr&7)<<3))] = f2bf(e);
      }
    }
  }

  // ---- r_qk / xv / LN1+relu -> A1 frags (regs); xv -> xvS ----
  i32x4 A1[2][4];
  #pragma unroll
  for (int mt = 0; mt < 2; ++mt) {
    const int j = jb + mt*16 + l15;
    float r8[4][8];
    float s1 = 0.f, s2 = 0.f;
    #pragma unroll
    for (int ks = 0; ks < 4; ++ks) {
      const int c0 = ks*32 + g4*8;
      const float* Up = U + ((size_t)nb*PP + j)*CC + c0;
      const float* qp = qq + (n*PP + j)*CC + c0;
      const float* vp = vv + (n*PP + j)*CC + c0;
      const f32x4 u0 = *(const f32x4*)(Up),    u1 = *(const f32x4*)(Up+4);
      const f32x4 q0 = *(const f32x4*)(qp),    q1 = *(const f32x4*)(qp+4);
      const f32x4 v0 = *(const f32x4*)(vp),    v1 = *(const f32x4*)(vp+4);
      const f32x4 k0 = *(const f32x4*)(kiS+c0), k1 = *(const f32x4*)(kiS+c0+4);
      const i32x4 ep = *(const i32x4*)(eS + j*CC + (c0 ^ ((j&7)<<3)));
      float Uf[8], Qf[8], Vf[8], Kf[8], Ef[8];
      #pragma unroll
      for (int e_ = 0; e_ < 4; ++e_) {
        Uf[e_] = u0[e_]; Uf[e_+4] = u1[e_];
        Qf[e_] = q0[e_]; Qf[e_+4] = q1[e_];
        Vf[e_] = v0[e_]; Vf[e_+4] = v1[e_];
        Kf[e_] = k0[e_]; Kf[e_+4] = k1[e_];
      }
      #pragma unroll
      for (int w_ = 0; w_ < 4; ++w_) {
        const uint32 eu = (uint32)ep[w_];
        Ef[2*w_]   = bf2f((unsigned short)(eu & 0xFFFFu));
        Ef[2*w_+1] = bf2f((unsigned short)(eu >> 16));
      }
      uint32 xw[4];
      #pragma unroll
      for (int w_ = 0; w_ < 4; ++w_) {
        const float xa = Vf[2*w_]   + Uf[2*w_]   + Ef[2*w_];
        const float xb = Vf[2*w_+1] + Uf[2*w_+1] + Ef[2*w_+1];
        xw[w_] = (uint32)f2bf(xa) | ((uint32)f2bf(xb) << 16);
      }
      *(i32x4*)(xvS + j*CC + (c0 ^ ((j&7)<<3))) =
          (i32x4){(int)xw[0],(int)xw[1],(int)xw[2],(int)xw[3]};
      #pragma unroll
      for (int e_ = 0; e_ < 8; ++e_) {
        const float rv = Kf[e_] - Qf[e_] + Uf[e_] + Ef[e_];
        r8[ks][e_] = rv; s1 += rv; s2 += rv*rv;
      }
    }
    s1 += __shfl_xor(s1, 16); s2 += __shfl_xor(s2, 16);
    s1 += __shfl_xor(s1, 32); s2 += __shfl_xor(s2, 32);
    const float mu = s1*(1.f/CC);
    const float rs = rsqrtf(s2*(1.f/CC) - mu*mu + EPS);
    #pragma unroll
    for (int ks = 0; ks < 4; ++ks) {
      const int c0 = ks*32 + g4*8;
      const f32x4 ga = *(const f32x4*)(g1S + c0), gb = *(const f32x4*)(g1S + c0 + 4);
      const f32x4 ba = *(const f32x4*)(b1lS + c0), bbv = *(const f32x4*)(b1lS + c0 + 4);
      uint32 pk[4];
      #pragma unroll
      for (int w_ = 0; w_ < 4; ++w_) {
        const int eA = 2*w_, eB = 2*w_+1;
        const float gA = (eA<4)?ga[eA]:gb[eA-4], gB = (eB<4)?ga[eB]:gb[eB-4];
        const float bA = (eA<4)?ba[eA]:bbv[eA-4], bB = (eB<4)?ba[eB]:bbv[eB-4];
        const float aA = fmaxf((r8[ks][eA]-mu)*rs*gA + bA, 0.f);
        const float aB = fmaxf((r8[ks][eB]-mu)*rs*gB + bB, 0.f);
        pk[w_] = (uint32)f2bf(aA) | ((uint32)f2bf(aB) << 16);
      }
      A1[mt][ks] = (i32x4){(int)pk[0],(int)pk[1],(int)pk[2],(int)pk[3]};
    }
  }

  // ---- GEMM1: acc1 = a @ w1^T ----
  f32x4 acc1[2][8];
  #pragma unroll
  for (int mt = 0; mt < 2; ++mt)
    #pragma unroll
    for (int nt = 0; nt < 8; ++nt) acc1[mt][nt] = (f32x4){0.f,0.f,0.f,0.f};
  #pragma unroll
  for (int ks = 0; ks < 4; ++ks) {
    #pragma unroll
    for (int nt = 0; nt < 8; ++nt) {
      const int co = nt*16 + l15;
      const i32x4 B = *(const i32x4*)(w1b + co*CC + ks*32 + g4*8);
      acc1[0][nt] = mfma_bf16(A1[0][ks], B, acc1[0][nt]);
      acc1[1][nt] = mfma_bf16(A1[1][ks], B, acc1[1][nt]);
    }
  }

  // ---- +b1, LN2+relu -> a2 (eS reused), read back A2 frags ----
  #pragma unroll
  for (int mt = 0; mt < 2; ++mt) {
    float mu[4], rsv[4];
    #pragma unroll
    for (int r = 0; r < 4; ++r) {
      float a = 0.f, b = 0.f;
      #pragma unroll
      for (int nt = 0; nt < 8; ++nt) {
        const float v = acc1[mt][nt][r] + bb1S[nt*16 + l15];
        acc1[mt][nt][r] = v;
        a += v; b += v*v;
      }
      a += __shfl_xor(a, 1); b += __shfl_xor(b, 1);
      a += __shfl_xor(a, 2); b += __shfl_xor(b, 2);
      a += __shfl_xor(a, 4); b += __shfl_xor(b, 4);
      a += __shfl_xor(a, 8); b += __shfl_xor(b, 8);
      mu[r]  = a*(1.f/CC);
      rsv[r] = rsqrtf(b*(1.f/CC) - mu[r]*mu[r] + EPS);
    }
    #pragma unroll
    for (int nt = 0; nt < 8; ++nt) {
      const int co = nt*16 + l15;
      const float g2v = g2S[co], b2v = b2lS[co];
      #pragma unroll
      for (int r = 0; r < 4; ++r) {
        const int jr = jb + mt*16 + g4*4 + r;
        const float a2 = fmaxf((acc1[mt][nt][r]-mu[r])*rsv[r]*g2v + b2v, 0.f);
        eS[jr*CC + (co ^ ((jr&7)<<3))] = f2bf(a2);
      }
    }
  }
  i32x4 A2[2][4];
  #pragma unroll
  for (int mt = 0; mt < 2; ++mt) {
    const int j = jb + mt*16 + l15;
    #pragma unroll
    for (int ks = 0; ks < 4; ++ks) {
      const int c0 = ks*32 + g4*8;
      A2[mt][ks] = *(const i32x4*)(eS + j*CC + (c0 ^ ((j&7)<<3)));
    }
  }

  // ---- GEMM2: logits = a2 @ w2^T ----
  f32x4 acc2[2][8];
  #pragma unroll
  for (int mt = 0; mt < 2; ++mt)
    #pragma unroll
    for (int nt = 0; nt < 8; ++nt) acc2[mt][nt] = (f32x4){0.f,0.f,0.f,0.f};
  #pragma unroll
  for (int ks = 0; ks < 4; ++ks) {
    #pragma unroll
    for (int nt = 0; nt < 8; ++nt) {
      const int co = nt*16 + l15;
      const i32x4 B = *(const i32x4*)(w2b + co*CC + ks*32 + g4*8);
      acc2[0][nt] = mfma_bf16(A2[0][ks], B, acc2[0][nt]);
      acc2[1][nt] = mfma_bf16(A2[1][ks], B, acc2[1][nt]);
    }
  }

  // ---- softmax over j (cross-wave via red[] in pool) + x_out ----
  float* redM = (float*)pool;          // 512 f
  float* redS = redM + 512;            // 512 f
  float* redA = redM + 1024;           // 512 f
  __syncthreads();                     // all h0S/pool reads done
  #pragma unroll
  for (int nt = 0; nt < 8; ++nt) {
    const int co = nt*16 + l15;
    const float b2v = bb2S[co];
    float m = -INFINITY;
    #pragma unroll
    for (int mt = 0; mt < 2; ++mt)
      #pragma unroll
      for (int r = 0; r < 4; ++r) {
        float lv = acc2[mt][nt][r] + b2v;
        if (mask_i) lv = NEGV;
        acc2[mt][nt][r] = lv;
        m = fmaxf(m, lv);
      }
    m = fmaxf(m, __shfl_xor(m, 16));
    m = fmaxf(m, __shfl_xor(m, 32));
    if (g4 == 0) redM[wave*CC + co] = m;
  }
  __syncthreads();
  #pragma unroll
  for (int nt = 0; nt < 8; ++nt) {
    const int co = nt*16 + l15;
    const float M = fmaxf(fmaxf(redM[co], redM[CC+co]),
                          fmaxf(redM[2*CC+co], redM[3*CC+co]));
    float S = 0.f, A = 0.f;
    #pragma unroll
    for (int mt = 0; mt < 2; ++mt)
      #pragma unroll
      for (int r = 0; r < 4; ++r) {
        const int jr = jb + mt*16 + g4*4 + r;
        const float pv = __expf(acc2[mt][nt][r] - M);
        const float xvv = bf2f(xvS[jr*CC + (co ^ ((jr&7)<<3))]);
        S += pv; A += pv*xvv;
      }
    S += __shfl_xor(S, 16); A += __shfl_xor(A, 16);
    S += __shfl_xor(S, 32); A += __shfl_xor(A, 32);
    if (g4 == 0) { redS[wave*CC + co] = S; redA[wave*CC + co] = A; }
  }
  __syncthreads();
  if (t < CC) {
    const float S = redS[t] + redS[CC+t] + redS[2*CC+t] + redS[3*CC+t];
    const float A = redA[t] + redA[CC+t] + redA[2*CC+t] + redA[3*CC+t];
    xout[nb*CC + t] = A / S;
  }
}

// ---------------- K3: A[r,u] / B[r,u] from e1 halves ----------------
extern "C" __global__ void __launch_bounds__(64)
k_e1(const float* __restrict__ xout, const float* __restrict__ e1,
     float* __restrict__ A, float* __restrict__ B) {
  const int row = blockIdx.x;
  const int t = threadIdx.x;
  __shared__ __align__(16) float xs[CC];
  xs[t]      = xout[row*CC + t];
  xs[t + 64] = xout[row*CC + t + 64];
  __syncthreads();
  const int u = t & 31;
  const int half = t >> 5;
  const float* er = e1 + u*257 + half*128;
  float s = 0.f;
  for (int cc2 = 0; cc2 < CC; ++cc2) s += xs[cc2]*er[cc2];
  (half ? B : A)[row*HID + u] = s;
}

// ===================== K4: MFMA edge-MLP + softmax -> new_p ================
// One (n,i) per block, 4 waves; wave w owns j in [w*32, w*32+32) (mt=0,1).
// h1 built directly in A-frag registers; mij = h1@e2^T (MFMA); LN in C/D
// layout; y -> LDS transpose; h2 = y@x1^T (MFMA); scalar tail + block softmax.
extern "C" __global__ void __launch_bounds__(256, 3)
k_newp2(const float* __restrict__ p, const float* __restrict__ Am,
        const float* __restrict__ Bm, const float* __restrict__ e1,
        const unsigned short* __restrict__ e2b,
        const unsigned short* __restrict__ x1bb,
        const float* __restrict__ x1b, const float* __restrict__ x2,
        const float* __restrict__ x2b, float* __restrict__ outp) {
  __shared__ __align__(16) unsigned short yS[CC*CC];    // 32KB
  __shared__ __align__(16) float p_sh[PP*4];
  __shared__ __align__(16) float AiS[HID], e1lS[HID], x1bS[HID], x2S[HID];
  __shared__ __align__(16) float redx[4];
  __shared__ __align__(16) float redv[20];

  const int nb = blockIdx.x;
  const int n = nb >> 7, ii = nb & 127;
  const int t = threadIdx.x;
  const int lane = t & 63, wave = t >> 6, l15 = lane & 15, g4 = lane >> 4;

  p_sh[t]     = p[n*PP*4 + t];
  p_sh[t+256] = p[n*PP*4 + t + 256];
  if (t < HID) {
    AiS[t]  = Am[nb*HID + t];
    e1lS[t] = e1[t*257 + 256];
    x1bS[t] = x1b[t];
    x2S[t]  = x2[t];
  }
  __syncthreads();

  const bool mask_i = (p_sh[ii*4] == 0.0f);
  const float pi0 = p_sh[ii*4+0], pi1 = p_sh[ii*4+1];
  const float pi2 = p_sh[ii*4+2], pi3 = p_sh[ii*4+3];

  // ---- h1 A-frags (registers, no LDS) ----
  i32x4 A1[2];
  #pragma unroll
  for (int mt = 0; mt < 2; ++mt) {
    const int j = wave*32 + mt*16 + l15;
    const float pd0 = pi0 - p_sh[j*4+0], pd1 = pi1 - p_sh[j*4+1];
    const float pd2 = pi2 - p_sh[j*4+2], pd3 = pi3 - p_sh[j*4+3];
    float nv = pd3*pd3 - (pd0*pd0 + pd1*pd1 + pd2*pd2);
    if (mask_i) nv = 0.f;
    const float* bp = Bm + (n*PP + j)*HID + g4*8;
    const f32x4 b0 = *(const f32x4*)bp, b1v = *(const f32x4*)(bp+4);
    float bf[8];
    #pragma unroll
    for (int e_ = 0; e_ < 8; ++e_) bf[e_] = (e_<4) ? b0[e_] : b1v[e_-4];
    uint32 pk[4];
    #pragma unroll
    for (int w_ = 0; w_ < 4; ++w_) {
      const int uA = g4*8 + 2*w_, uB = uA+1;
      const float hA = fmaxf(AiS[uA] + bf[2*w_]   + e1lS[uA]*nv, 0.f);
      const float hB = fmaxf(AiS[uB] + bf[2*w_+1] + e1lS[uB]*nv, 0.f);
      pk[w_] = (uint32)f2bf(hA) | ((uint32)f2bf(hB) << 16);
    }
    A1[mt] = (i32x4){(int)pk[0],(int)pk[1],(int)pk[2],(int)pk[3]};
  }

  // ---- GEMM-e2: mij = h1 @ e2^T (K=32) ----
  f32x4 accM[2][8];
  #pragma unroll
  for (int nt = 0; nt < 8; ++nt) {
    const int co = nt*16 + l15;
    const i32x4 B = *(const i32x4*)(e2b + co*HID + g4*8);
    f32x4 z = {0.f,0.f,0.f,0.f};
    accM[0][nt] = mfma_bf16(A1[0], B, z);
    f32x4 z2 = {0.f,0.f,0.f,0.f};
    accM[1][nt] = mfma_bf16(A1[1], B, z2);
  }

  // ---- relu, mask, LN (no affine) -> yS ----
  #pragma unroll
  for (int mt = 0; mt < 2; ++mt)
    #pragma unroll
    for (int r = 0; r < 4; ++r) {
      float a = 0.f, b = 0.f;
      #pragma unroll
      for (int nt = 0; nt < 8; ++nt) {
        float v = fmaxf(accM[mt][nt][r], 0.f);
        if (mask_i) v = NEGV;
        accM[mt][nt][r] = v;
        a += v; b += v*v;
      }
      a += __shfl_xor(a, 1); b += __shfl_xor(b, 1);
      a += __shfl_xor(a, 2); b += __shfl_xor(b, 2);
      a += __shfl_xor(a, 4); b += __shfl_xor(b, 4);
      a += __shfl_xor(a, 8); b += __shfl_xor(b, 8);
      const float mu = a*(1.f/CC);
      const float rs = rsqrtf(b*(1.f/CC) - mu*mu + EPS);
      const int jr = wave*32 + mt*16 + g4*4 + r;
      #pragma unroll
      for (int nt = 0; nt < 8; ++nt) {
        const int co = nt*16 + l15;
        yS[jr*CC + (co ^ ((jr&7)<<3))] = f2bf((accM[mt][nt][r]-mu)*rs);
      }
    }

  // ---- A-frags of y; GEMM-x1: h2 = y @ x1^T ----
  f32x4 accH[2][2];
  accH[0][0] = (f32x4){0.f,0.f,0.f,0.f}; accH[0][1] = accH[0][0];
  accH[1][0] = accH[0][0];               accH[1][1] = accH[0][0];
  #pragma unroll
  for (int ks = 0; ks < 4; ++ks) {
    const int c0 = ks*32 + g4*8;
    i32x4 A2[2];
    #pragma unroll
    for (int mt = 0; mt < 2; ++mt) {
      const int j = wave*32 + mt*16 + l15;
      A2[mt] = *(const i32x4*)(yS + j*CC + (c0 ^ ((j&7)<<3)));
    }
    #pragma unroll
    for (int nt = 0; nt < 2; ++nt) {
      const int u = nt*16 + l15;
      const i32x4 B = *(const i32x4*)(x1bb + u*CC + c0);
      accH[0][nt] = mfma_bf16(A2[0], B, accH[0][nt]);
      accH[1][nt] = mfma_bf16(A2[1], B, accH[1][nt]);
    }
  }

  // ---- s_j = relu(x2b + sum_u x2[u]*relu(h2+x1b)) ----
  const float x2b0 = x2b[0];
  float sj[2][4];
  #pragma unroll
  for (int mt = 0; mt < 2; ++mt)
    #pragma unroll
    for (int r = 0; r < 4; ++r) {
      float sv = 0.f;
      #pragma unroll
      for (int nt = 0; nt < 2; ++nt) {
        const int u = nt*16 + l15;
        sv += x2S[u]*fmaxf(accH[mt][nt][r] + x1bS[u], 0.f);
      }
      sv += __shfl_xor(sv, 1); sv += __shfl_xor(sv, 2);
      sv += __shfl_xor(sv, 4); sv += __shfl_xor(sv, 8);
      sj[mt][r] = fmaxf(x2b0 + sv, 0.f);
    }

  // ---- block softmax over j + weighted pij sums ----
  float mx = -INFINITY;
  #pragma unroll
  for (int mt = 0; mt < 2; ++mt)
    #pragma unroll
    for (int r = 0; r < 4; ++r) mx = fmaxf(mx, sj[mt][r]);
  mx = fmaxf(mx, __shfl_xor(mx, 16));
  mx = fmaxf(mx, __shfl_xor(mx, 32));
  if (lane == 0) redx[wave] = mx;
  __syncthreads();
  mx = fmaxf(fmaxf(redx[0], redx[1]), fmaxf(redx[2], redx[3]));

  float v0=0.f, v1=0.f, v2=0.f, v3=0.f, v4=0.f;
  #pragma unroll
  for (int mt = 0; mt < 2; ++mt)
    #pragma unroll
    for (int r = 0; r < 4; ++r) {
      const int jr = wave*32 + mt*16 + g4*4 + r;
      const float ev = __expf(sj[mt][r] - mx);
      const float pd0 = pi0 - p_sh[jr*4+0], pd1 = pi1 - p_sh[jr*4+1];
      const float pd2 = pi2 - p_sh[jr*4+2], pd3 = pi3 - p_sh[jr*4+3];
      v0 += ev; v1 += ev*pd0; v2 += ev*pd1; v3 += ev*pd2; v4 += ev*pd3;
    }
  v0 += __shfl_xor(v0, 16); v1 += __shfl_xor(v1, 16); v2 += __shfl_xor(v2, 16);
  v3 += __shfl_xor(v3, 16); v4 += __shfl_xor(v4, 16);
  v0 += __shfl_xor(v0, 32); v1 += __shfl_xor(v1, 32); v2 += __shfl_xor(v2, 32);
  v3 += __shfl_xor(v3, 32); v4 += __shfl_xor(v4, 32);
  if (lane == 0) {
    redv[wave*5+0] = v0; redv[wave*5+1] = v1; redv[wave*5+2] = v2;
    redv[wave*5+3] = v3; redv[wave*5+4] = v4;
  }
  __syncthreads();
  if (t < 4) {
    const float V0 = redv[0] + redv[5] + redv[10] + redv[15];
    const float num = redv[1+t] + redv[6+t] + redv[11+t] + redv[16+t];
    float regc = 0.f;
    for (int jj = 0; jj < PP; ++jj) regc += (p_sh[jj*4] != 0.f) ? 1.f : 0.f;
    const float pid = p_sh[ii*4 + t];
    float val = pid + num/(V0*regc);
    if (pid == 0.f) val = 0.f;
    outp[nb*4 + t] = val;
  }
}

// ---------------- launcher ----------------
extern "C" void kernel_launch(void* const* d_in, const int* in_sizes, int n_in,
                              void* d_out, int out_size, void* d_ws, size_t ws_size,
                              hipStream_t stream) {
  const float* x    = (const float*)d_in[0];
  const float* p    = (const float*)d_in[1];
  const float* U    = (const float*)d_in[2];
  const float* wq   = (const float*)d_in[3];
  const float* bq   = (const float*)d_in[4];
  const float* wk   = (const float*)d_in[5];
  const float* bk   = (const float*)d_in[6];
  const float* wv   = (const float*)d_in[7];
  const float* bv   = (const float*)d_in[8];
  const float* ln1g = (const float*)d_in[9];
  const float* ln1b = (const float*)d_in[10];
  const float* w1   = (const float*)d_in[11];
  const float* b1   = (const float*)d_in[12];
  const float* ln2g = (const float*)d_in[13];
  const float* ln2b = (const float*)d_in[14];
  const float* w2   = (const float*)d_in[15];
  const float* b2   = (const float*)d_in[16];
  const float* pe1  = (const float*)d_in[17];
  const float* pe2  = (const float*)d_in[18];
  const float* e1   = (const float*)d_in[19];
  const float* e2   = (const float*)d_in[20];
  const float* x1   = (const float*)d_in[21];
  const float* x1b  = (const float*)d_in[22];
  const float* x2   = (const float*)d_in[23];
  const float* x2b  = (const float*)d_in[24];

  float* xout = (float*)d_out;
  float* outp = xout + NN*PP*CC;

  float* ws = (float*)d_ws;
  float* q  = ws;                       // 262144 f
  float* k  = q + NN*PP*CC;             // 262144 f
  float* v  = k + NN*PP*CC;             // 262144 f
  float* A  = v + NN*PP*CC;             // 65536 f
  float* B  = A + NN*PP*HID;            // 65536 f
  unsigned short* wsb   = (unsigned short*)(B + NN*PP*HID);
  unsigned short* w1b   = wsb;            // 16384
  unsigned short* w2b   = wsb + 16384;    // 16384
  unsigned short* pe2b  = wsb + 32768;    // 4096
  unsigned short* e2b   = wsb + 36864;    // 4096
  unsigned short* x1bb  = wsb + 40960;    // 4096

  k_prep<<<176, 256, 0, stream>>>(w1, w2, pe2, e2, x1, w1b, w2b, pe2b, e2b, x1bb);
  k_qkv <<<NN*PP, 128, 0, stream>>>(x, wq, bq, wk, bk, wv, bv, q, k, v);
  k_attn3<<<NN*PP, 256, 0, stream>>>(q, k, v, p, U, pe1, pe2b, w1b, w2b,
                                     ln1g, ln1b, b1, ln2g, ln2b, b2, xout);
  k_e1  <<<NN*PP, 64, 0, stream>>>(xout, e1, A, B);
  k_newp2<<<NN*PP, 256, 0, stream>>>(p, A, B, e1, e2b, x1bb, x1b, x2, x2b, outp);
}